// Round 1
// baseline (671.036 us; speedup 1.0000x reference)
//
#include <hip/hip_runtime.h>
#include <hip/hip_bf16.h>

#define N_NODES  50000
#define N_EDGES  640000
#define IN_FEATS 512
#define HID      128
#define OUT_FEATS 128
#define N_GRAPHS 256

// ---------------- CSR build ----------------

__global__ void k_zero_cnt(int* __restrict__ cnt) {
    int i = blockIdx.x * blockDim.x + threadIdx.x;
    if (i < N_NODES) cnt[i] = 0;
}

__global__ void k_count(const int* __restrict__ col, int* __restrict__ cnt) {
    int e = blockIdx.x * blockDim.x + threadIdx.x;
    if (e < N_EDGES) atomicAdd(&cnt[col[e]], 1);
}

// single-block exclusive scan over 50000 counts; also derives dinv and cursor
__global__ void k_scan(const int* __restrict__ cnt, int* __restrict__ offs,
                       int* __restrict__ cursor, float* __restrict__ dinv) {
    __shared__ int sums[1024];
    const int T = 1024;
    int t = threadIdx.x;
    int chunk = (N_NODES + T - 1) / T;           // 49
    int lo = t * chunk;
    int hi = lo + chunk; if (hi > N_NODES) hi = N_NODES;
    int s = 0;
    for (int i = lo; i < hi; ++i) s += cnt[i];
    sums[t] = s;
    __syncthreads();
    for (int off = 1; off < T; off <<= 1) {
        int add = (t >= off) ? sums[t - off] : 0;
        __syncthreads();
        sums[t] += add;
        __syncthreads();
    }
    int run = (t == 0) ? 0 : sums[t - 1];
    for (int i = lo; i < hi; ++i) {
        offs[i] = run;
        cursor[i] = run;
        run += cnt[i];
        dinv[i] = rsqrtf((float)cnt[i] + 1.0f);   // +1 for self-loop
    }
    if (t == 0) offs[N_NODES] = N_EDGES;
}

__global__ void k_fill(const int* __restrict__ row, const int* __restrict__ col,
                       int* __restrict__ cursor, int* __restrict__ srcIdx) {
    int e = blockIdx.x * blockDim.x + threadIdx.x;
    if (e < N_EDGES) {
        int c = col[e];
        int p = atomicAdd(&cursor[c], 1);
        srcIdx[p] = row[e];
    }
}

// ---------------- GEMM: C[M,128] = A[M,K] @ B[K,128], fp32 ----------------

template <int K>
__global__ __launch_bounds__(256) void k_gemm(const float* __restrict__ A,
                                              const float* __restrict__ B,
                                              float* __restrict__ C, int M) {
    const int BM = 64, BN = 128, BK = 16;
    __shared__ float As[BK][BM];   // transposed A tile
    __shared__ float Bs[BK][BN];
    int tid = threadIdx.x;
    int m0 = blockIdx.x * BM;
    int ty = tid >> 4, tx = tid & 15;
    int r0 = ty * 4;     // 4 rows per thread
    int c0 = tx * 8;     // 8 cols per thread
    float acc[4][8];
#pragma unroll
    for (int i = 0; i < 4; ++i)
#pragma unroll
        for (int j = 0; j < 8; ++j) acc[i][j] = 0.f;

    for (int k0 = 0; k0 < K; k0 += BK) {
        // stage A: 64x16 (one float4 per thread)
        {
            int m = tid >> 2;
            int kq = (tid & 3) * 4;
            int gm = m0 + m; if (gm >= M) gm = M - 1;
            const float4 av = *(const float4*)(A + (size_t)gm * K + k0 + kq);
            As[kq + 0][m] = av.x; As[kq + 1][m] = av.y;
            As[kq + 2][m] = av.z; As[kq + 3][m] = av.w;
        }
        // stage B: 16x128 (two float4 per thread)
#pragma unroll
        for (int it = 0; it < 2; ++it) {
            int idx = tid + it * 256;      // 0..511 float4 slots
            int k = idx >> 5;
            int c = (idx & 31) * 4;
            *(float4*)&Bs[k][c] = *(const float4*)(B + (size_t)(k0 + k) * 128 + c);
        }
        __syncthreads();
#pragma unroll
        for (int kk = 0; kk < BK; ++kk) {
            float4 a  = *(const float4*)&As[kk][r0];
            float4 b0 = *(const float4*)&Bs[kk][c0];
            float4 b1 = *(const float4*)&Bs[kk][c0 + 4];
            float av[4] = {a.x, a.y, a.z, a.w};
            float bv[8] = {b0.x, b0.y, b0.z, b0.w, b1.x, b1.y, b1.z, b1.w};
#pragma unroll
            for (int i = 0; i < 4; ++i)
#pragma unroll
                for (int j = 0; j < 8; ++j) acc[i][j] += av[i] * bv[j];
        }
        __syncthreads();
    }
#pragma unroll
    for (int i = 0; i < 4; ++i) {
        int gm = m0 + r0 + i;
        if (gm < M) {
            *(float4*)(C + (size_t)gm * 128 + c0)     = make_float4(acc[i][0], acc[i][1], acc[i][2], acc[i][3]);
            *(float4*)(C + (size_t)gm * 128 + c0 + 4) = make_float4(acc[i][4], acc[i][5], acc[i][6], acc[i][7]);
        }
    }
}

// ---------------- aggregation: one block (128 thr) per node ----------------

__global__ void k_agg(const float* __restrict__ t, const int* __restrict__ offs,
                      const int* __restrict__ srcIdx, const float* __restrict__ dinv,
                      const float* __restrict__ bias, float* __restrict__ out,
                      int do_relu) {
    int i = blockIdx.x;
    int f = threadIdx.x;   // 0..127
    float di = dinv[i];
    float s = t[(size_t)i * 128 + f] * di;     // self-loop term (inner)
    int lo = offs[i], hi = offs[i + 1];
    for (int e = lo; e < hi; ++e) {
        int sn = srcIdx[e];
        s += t[(size_t)sn * 128 + f] * dinv[sn];
    }
    float v = s * di + bias[f];
    if (do_relu) v = fmaxf(v, 0.f);
    out[(size_t)i * 128 + f] = v;
}

// ---------------- global add pool (batch is sorted) ----------------

__global__ void k_gstart(const int* __restrict__ batch, int* __restrict__ gstart) {
    int i = blockIdx.x * blockDim.x + threadIdx.x;
    if (i >= N_NODES) return;
    int b = batch[i];
    int bp = (i == 0) ? -1 : batch[i - 1];
    for (int g = bp + 1; g <= b; ++g) gstart[g] = i;
    if (i == N_NODES - 1) {
        for (int g = b + 1; g <= N_GRAPHS; ++g) gstart[g] = N_NODES;
    }
}

__global__ void k_pool(const float* __restrict__ h, const int* __restrict__ gstart,
                       float* __restrict__ hs) {
    int g = blockIdx.x;
    int f = threadIdx.x;  // 0..127
    float s = 0.f;
    int lo = gstart[g], hi = gstart[g + 1];
    for (int r = lo; r < hi; ++r) s += h[(size_t)r * 128 + f];
    hs[(size_t)g * 128 + f] = s;
}

// ---------------- launch ----------------

extern "C" void kernel_launch(void* const* d_in, const int* in_sizes, int n_in,
                              void* d_out, int out_size, void* d_ws, size_t ws_size,
                              hipStream_t stream) {
    const float* x  = (const float*)d_in[0];
    const float* W1 = (const float*)d_in[1];
    const float* b1 = (const float*)d_in[2];
    const float* W2 = (const float*)d_in[3];
    const float* b2 = (const float*)d_in[4];
    const int*   ei = (const int*)d_in[5];
    const int*   batch = (const int*)d_in[6];
    const int* row = ei;              // edge_index[0] = source
    const int* col = ei + N_EDGES;    // edge_index[1] = target

    float* out_hs = (float*)d_out;                       // [256,128]
    float* out_h  = (float*)d_out + N_GRAPHS * OUT_FEATS; // [50000,128]

    // workspace layout
    char* ws = (char*)d_ws;
    float* t    = (float*)ws;                                  // 50000*128 f32
    float* h1   = (float*)(ws + 25600000);                     // 50000*128 f32
    float* dinv = (float*)(ws + 51200000);                     // 50000 f32
    int*   cnt    = (int*)(ws + 51400000);                     // 50000 i32
    int*   offs   = (int*)(ws + 51600000);                     // 50001 i32
    int*   cursor = (int*)(ws + 51800004);                     // 50000 i32
    int*   srcIdx = (int*)(ws + 52000004);                     // 640000 i32
    int*   gstart = (int*)(ws + 54560004);                     // 257 i32

    const int TB = 256;
    // CSR build
    k_zero_cnt<<<(N_NODES + TB - 1) / TB, TB, 0, stream>>>(cnt);
    k_count<<<(N_EDGES + TB - 1) / TB, TB, 0, stream>>>(col, cnt);
    k_scan<<<1, 1024, 0, stream>>>(cnt, offs, cursor, dinv);
    k_fill<<<(N_EDGES + TB - 1) / TB, TB, 0, stream>>>(row, col, cursor, srcIdx);
    // graph boundaries (independent; sorted batch)
    k_gstart<<<(N_NODES + TB - 1) / TB, TB, 0, stream>>>(batch, gstart);

    const int GB = (N_NODES + 63) / 64;   // 782
    // layer 1
    k_gemm<IN_FEATS><<<GB, 256, 0, stream>>>(x, W1, t, N_NODES);
    k_agg<<<N_NODES, 128, 0, stream>>>(t, offs, srcIdx, dinv, b1, h1, 1);
    // layer 2
    k_gemm<HID><<<GB, 256, 0, stream>>>(h1, W2, t, N_NODES);
    k_agg<<<N_NODES, 128, 0, stream>>>(t, offs, srcIdx, dinv, b2, out_h, 0);
    // pool
    k_pool<<<N_GRAPHS, 128, 0, stream>>>(out_h, gstart, out_hs);
}

// Round 2
// 557.146 us; speedup vs baseline: 1.2044x; 1.2044x over previous
//
#include <hip/hip_runtime.h>
#include <hip/hip_bf16.h>

#define N_NODES  50000
#define N_EDGES  640000
#define IN_FEATS 512
#define HID      128
#define OUT_FEATS 128
#define N_GRAPHS 256

#define SCAN_CHUNK 1024
#define SCAN_BLOCKS ((N_NODES + SCAN_CHUNK - 1) / SCAN_CHUNK)   // 49

// ---------------- CSR build ----------------

__global__ void k_count(const int* __restrict__ col, int* __restrict__ cnt) {
    int e = blockIdx.x * blockDim.x + threadIdx.x;
    if (e < N_EDGES) atomicAdd(&cnt[col[e]], 1);
}

// phase A: per-block scan of 1024 counts (4/thread), write local excl offsets + block sum
__global__ __launch_bounds__(256) void k_scan_a(const int* __restrict__ cnt,
                                                int* __restrict__ offs,
                                                int* __restrict__ bsum) {
    __shared__ int sums[256];
    int t = threadIdx.x;
    int base = blockIdx.x * SCAN_CHUNK + t * 4;
    int c0 = 0, c1 = 0, c2 = 0, c3 = 0;
    if (base + 3 < N_NODES) {
        int4 v = *(const int4*)(cnt + base);
        c0 = v.x; c1 = v.y; c2 = v.z; c3 = v.w;
    } else {
        if (base + 0 < N_NODES) c0 = cnt[base + 0];
        if (base + 1 < N_NODES) c1 = cnt[base + 1];
        if (base + 2 < N_NODES) c2 = cnt[base + 2];
        if (base + 3 < N_NODES) c3 = cnt[base + 3];
    }
    int ts = c0 + c1 + c2 + c3;
    sums[t] = ts;
    __syncthreads();
#pragma unroll
    for (int off = 1; off < 256; off <<= 1) {
        int add = (t >= off) ? sums[t - off] : 0;
        __syncthreads();
        sums[t] += add;
        __syncthreads();
    }
    int ex = sums[t] - ts;   // exclusive prefix of this thread within block
    if (base + 3 < N_NODES) {
        int4 o;
        o.x = ex; o.y = ex + c0; o.z = ex + c0 + c1; o.w = ex + c0 + c1 + c2;
        *(int4*)(offs + base) = o;
    } else {
        if (base + 0 < N_NODES) offs[base + 0] = ex;
        if (base + 1 < N_NODES) offs[base + 1] = ex + c0;
        if (base + 2 < N_NODES) offs[base + 2] = ex + c0 + c1;
        if (base + 3 < N_NODES) offs[base + 3] = ex + c0 + c1 + c2;
    }
    if (t == 255) bsum[blockIdx.x] = sums[255];
}

// phase B: scan the 49 block sums (single small block)
__global__ void k_scan_b(int* __restrict__ bsum, int* __restrict__ boff) {
    __shared__ int s[64];
    int t = threadIdx.x;   // 64 threads
    int v = (t < SCAN_BLOCKS) ? bsum[t] : 0;
    s[t] = v;
    __syncthreads();
#pragma unroll
    for (int off = 1; off < 64; off <<= 1) {
        int add = (t >= off) ? s[t - off] : 0;
        __syncthreads();
        s[t] += add;
        __syncthreads();
    }
    if (t < SCAN_BLOCKS) boff[t] = s[t] - v;   // exclusive
}

// phase C: add block offset; emit offs/cursor/dinv
__global__ __launch_bounds__(256) void k_scan_c(const int* __restrict__ cnt,
                                                const int* __restrict__ boff,
                                                int* __restrict__ offs,
                                                int* __restrict__ cursor,
                                                float* __restrict__ dinv) {
    int t = threadIdx.x;
    int b = blockIdx.x;
    int add = boff[b];
    int base = b * SCAN_CHUNK + t * 4;
    if (base + 3 < N_NODES) {
        int4 o = *(const int4*)(offs + base);
        o.x += add; o.y += add; o.z += add; o.w += add;
        *(int4*)(offs + base) = o;
        *(int4*)(cursor + base) = o;
        int4 c = *(const int4*)(cnt + base);
        float4 d;
        d.x = rsqrtf((float)c.x + 1.0f);
        d.y = rsqrtf((float)c.y + 1.0f);
        d.z = rsqrtf((float)c.z + 1.0f);
        d.w = rsqrtf((float)c.w + 1.0f);
        *(float4*)(dinv + base) = d;
    } else {
#pragma unroll
        for (int j = 0; j < 4; ++j) {
            int i = base + j;
            if (i < N_NODES) {
                int o = offs[i] + add;
                offs[i] = o; cursor[i] = o;
                dinv[i] = rsqrtf((float)cnt[i] + 1.0f);
            }
        }
    }
    if (b == 0 && t == 0) offs[N_NODES] = N_EDGES;
}

__global__ void k_fill(const int* __restrict__ row, const int* __restrict__ col,
                       int* __restrict__ cursor, int* __restrict__ srcIdx) {
    int e = blockIdx.x * blockDim.x + threadIdx.x;
    if (e < N_EDGES) {
        int c = col[e];
        int p = atomicAdd(&cursor[c], 1);
        srcIdx[p] = row[e];
    }
}

// ---------------- GEMM: C[M,128] = A[M,K] @ B[K,128], fp32 ----------------

template <int K>
__global__ __launch_bounds__(256) void k_gemm(const float* __restrict__ A,
                                              const float* __restrict__ B,
                                              float* __restrict__ C, int M) {
    const int BM = 64, BK = 16;
    __shared__ float As[BK][BM];   // transposed A tile
    __shared__ float Bs[BK][128];
    int tid = threadIdx.x;
    int m0 = blockIdx.x * BM;
    int ty = tid >> 4, tx = tid & 15;
    int r0 = ty * 4;     // 4 rows per thread
    int c0 = tx * 8;     // 8 cols per thread
    float acc[4][8];
#pragma unroll
    for (int i = 0; i < 4; ++i)
#pragma unroll
        for (int j = 0; j < 8; ++j) acc[i][j] = 0.f;

    for (int k0 = 0; k0 < K; k0 += BK) {
        {
            int m = tid >> 2;
            int kq = (tid & 3) * 4;
            int gm = m0 + m; if (gm >= M) gm = M - 1;
            const float4 av = *(const float4*)(A + (size_t)gm * K + k0 + kq);
            As[kq + 0][m] = av.x; As[kq + 1][m] = av.y;
            As[kq + 2][m] = av.z; As[kq + 3][m] = av.w;
        }
#pragma unroll
        for (int it = 0; it < 2; ++it) {
            int idx = tid + it * 256;      // 0..511 float4 slots
            int k = idx >> 5;
            int c = (idx & 31) * 4;
            *(float4*)&Bs[k][c] = *(const float4*)(B + (size_t)(k0 + k) * 128 + c);
        }
        __syncthreads();
#pragma unroll
        for (int kk = 0; kk < BK; ++kk) {
            float4 a  = *(const float4*)&As[kk][r0];
            float4 b0 = *(const float4*)&Bs[kk][c0];
            float4 b1 = *(const float4*)&Bs[kk][c0 + 4];
            float av[4] = {a.x, a.y, a.z, a.w};
            float bv[8] = {b0.x, b0.y, b0.z, b0.w, b1.x, b1.y, b1.z, b1.w};
#pragma unroll
            for (int i = 0; i < 4; ++i)
#pragma unroll
                for (int j = 0; j < 8; ++j) acc[i][j] += av[i] * bv[j];
        }
        __syncthreads();
    }
#pragma unroll
    for (int i = 0; i < 4; ++i) {
        int gm = m0 + r0 + i;
        if (gm < M) {
            *(float4*)(C + (size_t)gm * 128 + c0)     = make_float4(acc[i][0], acc[i][1], acc[i][2], acc[i][3]);
            *(float4*)(C + (size_t)gm * 128 + c0 + 4) = make_float4(acc[i][4], acc[i][5], acc[i][6], acc[i][7]);
        }
    }
}

// ---------------- aggregation: one block (128 thr) per node ----------------

__global__ void k_agg(const float* __restrict__ t, const int* __restrict__ offs,
                      const int* __restrict__ srcIdx, const float* __restrict__ dinv,
                      const float* __restrict__ bias, float* __restrict__ out,
                      int do_relu) {
    int i = blockIdx.x;
    int f = threadIdx.x;   // 0..127
    float di = dinv[i];
    float s = t[(size_t)i * 128 + f] * di;     // self-loop term (inner)
    int lo = offs[i], hi = offs[i + 1];
    for (int e = lo; e < hi; ++e) {
        int sn = srcIdx[e];
        s += t[(size_t)sn * 128 + f] * dinv[sn];
    }
    float v = s * di + bias[f];
    if (do_relu) v = fmaxf(v, 0.f);
    out[(size_t)i * 128 + f] = v;
}

// ---------------- global add pool (batch is sorted) ----------------

__global__ void k_gstart(const int* __restrict__ batch, int* __restrict__ gstart) {
    int i = blockIdx.x * blockDim.x + threadIdx.x;
    if (i >= N_NODES) return;
    int b = batch[i];
    int bp = (i == 0) ? -1 : batch[i - 1];
    for (int g = bp + 1; g <= b; ++g) gstart[g] = i;
    if (i == N_NODES - 1) {
        for (int g = b + 1; g <= N_GRAPHS; ++g) gstart[g] = N_NODES;
    }
}

__global__ void k_pool(const float* __restrict__ h, const int* __restrict__ gstart,
                       float* __restrict__ hs) {
    int g = blockIdx.x;
    int f = threadIdx.x;  // 0..127
    float s = 0.f;
    int lo = gstart[g], hi = gstart[g + 1];
    for (int r = lo; r < hi; ++r) s += h[(size_t)r * 128 + f];
    hs[(size_t)g * 128 + f] = s;
}

// ---------------- launch ----------------

extern "C" void kernel_launch(void* const* d_in, const int* in_sizes, int n_in,
                              void* d_out, int out_size, void* d_ws, size_t ws_size,
                              hipStream_t stream) {
    const float* x  = (const float*)d_in[0];
    const float* W1 = (const float*)d_in[1];
    const float* b1 = (const float*)d_in[2];
    const float* W2 = (const float*)d_in[3];
    const float* b2 = (const float*)d_in[4];
    const int*   ei = (const int*)d_in[5];
    const int*   batch = (const int*)d_in[6];
    const int* row = ei;              // edge_index[0] = source
    const int* col = ei + N_EDGES;    // edge_index[1] = target

    float* out_hs = (float*)d_out;                        // [256,128]
    float* out_h  = (float*)d_out + N_GRAPHS * OUT_FEATS; // [50000,128]

    // workspace layout
    char* ws = (char*)d_ws;
    float* t    = (float*)ws;                                  // 50000*128 f32
    float* h1   = (float*)(ws + 25600000);                     // 50000*128 f32
    float* dinv = (float*)(ws + 51200000);                     // 50000 f32
    int*   cnt    = (int*)(ws + 51400000);                     // 50000 i32
    int*   offs   = (int*)(ws + 51600000);                     // 50001 i32
    int*   cursor = (int*)(ws + 51800004);                     // 50000 i32
    int*   srcIdx = (int*)(ws + 52000004);                     // 640000 i32
    int*   gstart = (int*)(ws + 54560004);                     // 257 i32
    int*   bsum   = (int*)(ws + 54561032);                     // 49 i32
    int*   boff   = (int*)(ws + 54561232);                     // 49 i32

    const int TB = 256;
    // CSR build
    hipMemsetAsync(cnt, 0, N_NODES * sizeof(int), stream);
    k_count<<<(N_EDGES + TB - 1) / TB, TB, 0, stream>>>(col, cnt);
    k_scan_a<<<SCAN_BLOCKS, 256, 0, stream>>>(cnt, offs, bsum);
    k_scan_b<<<1, 64, 0, stream>>>(bsum, boff);
    k_scan_c<<<SCAN_BLOCKS, 256, 0, stream>>>(cnt, boff, offs, cursor, dinv);
    k_fill<<<(N_EDGES + TB - 1) / TB, TB, 0, stream>>>(row, col, cursor, srcIdx);
    // graph boundaries (independent; sorted batch)
    k_gstart<<<(N_NODES + TB - 1) / TB, TB, 0, stream>>>(batch, gstart);

    const int GB = (N_NODES + 63) / 64;   // 782
    // layer 1
    k_gemm<IN_FEATS><<<GB, 256, 0, stream>>>(x, W1, t, N_NODES);
    k_agg<<<N_NODES, 128, 0, stream>>>(t, offs, srcIdx, dinv, b1, h1, 1);
    // layer 2
    k_gemm<HID><<<GB, 256, 0, stream>>>(h1, W2, t, N_NODES);
    k_agg<<<N_NODES, 128, 0, stream>>>(t, offs, srcIdx, dinv, b2, out_h, 0);
    // pool
    k_pool<<<N_GRAPHS, 128, 0, stream>>>(out_h, gstart, out_hs);
}

// Round 3
// 493.022 us; speedup vs baseline: 1.3611x; 1.1301x over previous
//
#include <hip/hip_runtime.h>
#include <hip/hip_bf16.h>

#define N_NODES  50000
#define N_EDGES  640000
#define IN_FEATS 512
#define HID      128
#define OUT_FEATS 128
#define N_GRAPHS 256

#define SCAN_CHUNK 1024
#define SCAN_BLOCKS ((N_NODES + SCAN_CHUNK - 1) / SCAN_CHUNK)   // 49

typedef __attribute__((ext_vector_type(8))) short short8;
typedef __attribute__((ext_vector_type(4))) float f32x4;

// ---------------- CSR build ----------------

__global__ void k_count(const int* __restrict__ col, int* __restrict__ cnt) {
    int e = blockIdx.x * blockDim.x + threadIdx.x;
    if (e < N_EDGES) atomicAdd(&cnt[col[e]], 1);
}

__global__ __launch_bounds__(256) void k_scan_a(const int* __restrict__ cnt,
                                                int* __restrict__ offs,
                                                int* __restrict__ bsum) {
    __shared__ int sums[256];
    int t = threadIdx.x;
    int base = blockIdx.x * SCAN_CHUNK + t * 4;
    int c0 = 0, c1 = 0, c2 = 0, c3 = 0;
    if (base + 3 < N_NODES) {
        int4 v = *(const int4*)(cnt + base);
        c0 = v.x; c1 = v.y; c2 = v.z; c3 = v.w;
    } else {
        if (base + 0 < N_NODES) c0 = cnt[base + 0];
        if (base + 1 < N_NODES) c1 = cnt[base + 1];
        if (base + 2 < N_NODES) c2 = cnt[base + 2];
    }
    int ts = c0 + c1 + c2 + c3;
    sums[t] = ts;
    __syncthreads();
#pragma unroll
    for (int off = 1; off < 256; off <<= 1) {
        int add = (t >= off) ? sums[t - off] : 0;
        __syncthreads();
        sums[t] += add;
        __syncthreads();
    }
    int ex = sums[t] - ts;
    if (base + 3 < N_NODES) {
        int4 o;
        o.x = ex; o.y = ex + c0; o.z = ex + c0 + c1; o.w = ex + c0 + c1 + c2;
        *(int4*)(offs + base) = o;
    } else {
        if (base + 0 < N_NODES) offs[base + 0] = ex;
        if (base + 1 < N_NODES) offs[base + 1] = ex + c0;
        if (base + 2 < N_NODES) offs[base + 2] = ex + c0 + c1;
    }
    if (t == 255) bsum[blockIdx.x] = sums[255];
}

__global__ void k_scan_b(int* __restrict__ bsum, int* __restrict__ boff) {
    __shared__ int s[64];
    int t = threadIdx.x;
    int v = (t < SCAN_BLOCKS) ? bsum[t] : 0;
    s[t] = v;
    __syncthreads();
#pragma unroll
    for (int off = 1; off < 64; off <<= 1) {
        int add = (t >= off) ? s[t - off] : 0;
        __syncthreads();
        s[t] += add;
        __syncthreads();
    }
    if (t < SCAN_BLOCKS) boff[t] = s[t] - v;
}

__global__ __launch_bounds__(256) void k_scan_c(const int* __restrict__ cnt,
                                                const int* __restrict__ boff,
                                                int* __restrict__ offs,
                                                int* __restrict__ cursor,
                                                float* __restrict__ dinv) {
    int t = threadIdx.x;
    int b = blockIdx.x;
    int add = boff[b];
    int base = b * SCAN_CHUNK + t * 4;
    if (base + 3 < N_NODES) {
        int4 o = *(const int4*)(offs + base);
        o.x += add; o.y += add; o.z += add; o.w += add;
        *(int4*)(offs + base) = o;
        *(int4*)(cursor + base) = o;
        int4 c = *(const int4*)(cnt + base);
        float4 d;
        d.x = rsqrtf((float)c.x + 1.0f);
        d.y = rsqrtf((float)c.y + 1.0f);
        d.z = rsqrtf((float)c.z + 1.0f);
        d.w = rsqrtf((float)c.w + 1.0f);
        *(float4*)(dinv + base) = d;
    } else {
#pragma unroll
        for (int j = 0; j < 4; ++j) {
            int i = base + j;
            if (i < N_NODES) {
                int o = offs[i] + add;
                offs[i] = o; cursor[i] = o;
                dinv[i] = rsqrtf((float)cnt[i] + 1.0f);
            }
        }
    }
    if (b == 0 && t == 0) offs[N_NODES] = N_EDGES;
}

__global__ void k_fill(const int* __restrict__ row, const int* __restrict__ col,
                       int* __restrict__ cursor, int* __restrict__ srcIdx) {
    int e = blockIdx.x * blockDim.x + threadIdx.x;
    if (e < N_EDGES) {
        int c = col[e];
        int p = atomicAdd(&cursor[c], 1);
        srcIdx[p] = row[e];
    }
}

// ---------------- W transpose+convert: Wt[n][k] = bf16(W[k][n]) ----------------

template <int K>
__global__ void k_cvt_wt(const float* __restrict__ W, unsigned short* __restrict__ Wt) {
    int idx = blockIdx.x * blockDim.x + threadIdx.x;   // K*128 total
    if (idx >= K * 128) return;
    int n = idx & 127;
    int k = idx >> 7;
    __hip_bfloat16 h = __float2bfloat16(W[(size_t)k * 128 + n]);
    Wt[(size_t)n * K + k] = *(unsigned short*)&h;
}

// ------- MFMA GEMM1: C[M,128] = A[M,K]fp32 @ Wt[128][K]bf16^T, fp32 out -------
// BM=64, BN=128, BK=32; 256 thr = 4 waves; wave w -> rows w*16..w*16+15

template <int K>
__global__ __launch_bounds__(256) void k_gemm_mfma(const float* __restrict__ A,
                                                   const unsigned short* __restrict__ Bt,
                                                   float* __restrict__ C, int M) {
    __shared__ unsigned short As[4][64][8];   // [kq][row][8k]  4 KB
    __shared__ unsigned short Bs[4][128][8];  // [kq][n][8k]    8 KB
    int tid = threadIdx.x;
    int wave = tid >> 6;
    int lane = tid & 63;
    int quad = lane >> 4;
    int l15 = lane & 15;
    int m0 = blockIdx.x * 64;

    f32x4 acc[8];
#pragma unroll
    for (int nt = 0; nt < 8; ++nt) acc[nt] = (f32x4){0.f, 0.f, 0.f, 0.f};

    // staging assignments (wave-uniform kq -> conflict-free LDS writes)
    int ar = lane;            // A row 0..63
    int akq = wave;           // A k-octet 0..3
    int gm_a = m0 + ar; if (gm_a >= M) gm_a = M - 1;
    const float* ap_base = A + (size_t)gm_a * K + akq * 8;

    for (int k0 = 0; k0 < K; k0 += 32) {
        // stage A: 64 rows x 32 k, convert fp32->bf16
        {
            const float* ap = ap_base + k0;
            float4 v0 = *(const float4*)ap;
            float4 v1 = *(const float4*)(ap + 4);
            unsigned short u[8];
            float f[8] = {v0.x, v0.y, v0.z, v0.w, v1.x, v1.y, v1.z, v1.w};
#pragma unroll
            for (int j = 0; j < 8; ++j) {
                __hip_bfloat16 h = __float2bfloat16(f[j]);
                u[j] = *(unsigned short*)&h;
            }
            short8 pk;
#pragma unroll
            for (int j = 0; j < 8; ++j) pk[j] = (short)u[j];
            *(short8*)&As[akq][ar][0] = pk;
        }
        // stage B: 128 n x 32 k (already bf16, n-major in global)
#pragma unroll
        for (int i = 0; i < 2; ++i) {
            int slot = tid + i * 256;       // 0..511
            int bkq = slot >> 7;            // 0..3
            int n = slot & 127;
            short8 bv = *(const short8*)(Bt + (size_t)n * K + k0 + bkq * 8);
            *(short8*)&Bs[bkq][n][0] = bv;
        }
        __syncthreads();
        short8 a = *(short8*)&As[quad][wave * 16 + l15][0];
#pragma unroll
        for (int nt = 0; nt < 8; ++nt) {
            short8 b = *(short8*)&Bs[quad][nt * 16 + l15][0];
            acc[nt] = __builtin_amdgcn_mfma_f32_16x16x32_bf16(a, b, acc[nt], 0, 0, 0);
        }
        __syncthreads();
    }
    // epilogue: C/D layout col=lane&15, row=quad*4+reg
    int row_base = m0 + wave * 16 + quad * 4;
#pragma unroll
    for (int nt = 0; nt < 8; ++nt) {
#pragma unroll
        for (int r2 = 0; r2 < 4; ++r2) {
            int gm = row_base + r2;
            if (gm < M) C[(size_t)gm * 128 + nt * 16 + l15] = acc[nt][r2];
        }
    }
}

// ---------------- fp32 vector GEMM (layer 2, K=128) ----------------

template <int K>
__global__ __launch_bounds__(256) void k_gemm(const float* __restrict__ A,
                                              const float* __restrict__ B,
                                              float* __restrict__ C, int M) {
    const int BM = 64, BK = 16;
    __shared__ float As[BK][BM];
    __shared__ float Bs[BK][128];
    int tid = threadIdx.x;
    int m0 = blockIdx.x * BM;
    int ty = tid >> 4, tx = tid & 15;
    int r0 = ty * 4;
    int c0 = tx * 8;
    float acc[4][8];
#pragma unroll
    for (int i = 0; i < 4; ++i)
#pragma unroll
        for (int j = 0; j < 8; ++j) acc[i][j] = 0.f;

    for (int k0 = 0; k0 < K; k0 += BK) {
        {
            int m = tid >> 2;
            int kq = (tid & 3) * 4;
            int gm = m0 + m; if (gm >= M) gm = M - 1;
            const float4 av = *(const float4*)(A + (size_t)gm * K + k0 + kq);
            As[kq + 0][m] = av.x; As[kq + 1][m] = av.y;
            As[kq + 2][m] = av.z; As[kq + 3][m] = av.w;
        }
#pragma unroll
        for (int it = 0; it < 2; ++it) {
            int idx = tid + it * 256;
            int k = idx >> 5;
            int c = (idx & 31) * 4;
            *(float4*)&Bs[k][c] = *(const float4*)(B + (size_t)(k0 + k) * 128 + c);
        }
        __syncthreads();
#pragma unroll
        for (int kk = 0; kk < BK; ++kk) {
            float4 a  = *(const float4*)&As[kk][r0];
            float4 b0 = *(const float4*)&Bs[kk][c0];
            float4 b1 = *(const float4*)&Bs[kk][c0 + 4];
            float av[4] = {a.x, a.y, a.z, a.w};
            float bv[8] = {b0.x, b0.y, b0.z, b0.w, b1.x, b1.y, b1.z, b1.w};
#pragma unroll
            for (int i = 0; i < 4; ++i)
#pragma unroll
                for (int j = 0; j < 8; ++j) acc[i][j] += av[i] * bv[j];
        }
        __syncthreads();
    }
#pragma unroll
    for (int i = 0; i < 4; ++i) {
        int gm = m0 + r0 + i;
        if (gm < M) {
            *(float4*)(C + (size_t)gm * 128 + c0)     = make_float4(acc[i][0], acc[i][1], acc[i][2], acc[i][3]);
            *(float4*)(C + (size_t)gm * 128 + c0 + 4) = make_float4(acc[i][4], acc[i][5], acc[i][6], acc[i][7]);
        }
    }
}

// ---------------- aggregation: one block (128 thr) per node ----------------

__global__ void k_agg(const float* __restrict__ t, const int* __restrict__ offs,
                      const int* __restrict__ srcIdx, const float* __restrict__ dinv,
                      const float* __restrict__ bias, float* __restrict__ out,
                      int do_relu) {
    int i = blockIdx.x;
    int f = threadIdx.x;
    float di = dinv[i];
    float s = t[(size_t)i * 128 + f] * di;
    int lo = offs[i], hi = offs[i + 1];
    for (int e = lo; e < hi; ++e) {
        int sn = srcIdx[e];
        s += t[(size_t)sn * 128 + f] * dinv[sn];
    }
    float v = s * di + bias[f];
    if (do_relu) v = fmaxf(v, 0.f);
    out[(size_t)i * 128 + f] = v;
}

// ---------------- global add pool ----------------

__global__ void k_gstart(const int* __restrict__ batch, int* __restrict__ gstart) {
    int i = blockIdx.x * blockDim.x + threadIdx.x;
    if (i >= N_NODES) return;
    int b = batch[i];
    int bp = (i == 0) ? -1 : batch[i - 1];
    for (int g = bp + 1; g <= b; ++g) gstart[g] = i;
    if (i == N_NODES - 1) {
        for (int g = b + 1; g <= N_GRAPHS; ++g) gstart[g] = N_NODES;
    }
}

__global__ void k_pool(const float* __restrict__ h, const int* __restrict__ gstart,
                       float* __restrict__ hs) {
    int g = blockIdx.x;
    int f = threadIdx.x;
    float s = 0.f;
    int lo = gstart[g], hi = gstart[g + 1];
    for (int r = lo; r < hi; ++r) s += h[(size_t)r * 128 + f];
    hs[(size_t)g * 128 + f] = s;
}

// ---------------- launch ----------------

extern "C" void kernel_launch(void* const* d_in, const int* in_sizes, int n_in,
                              void* d_out, int out_size, void* d_ws, size_t ws_size,
                              hipStream_t stream) {
    const float* x  = (const float*)d_in[0];
    const float* W1 = (const float*)d_in[1];
    const float* b1 = (const float*)d_in[2];
    const float* W2 = (const float*)d_in[3];
    const float* b2 = (const float*)d_in[4];
    const int*   ei = (const int*)d_in[5];
    const int*   batch = (const int*)d_in[6];
    const int* row = ei;
    const int* col = ei + N_EDGES;

    float* out_hs = (float*)d_out;
    float* out_h  = (float*)d_out + N_GRAPHS * OUT_FEATS;

    // workspace layout (16B-aligned blocks)
    char* ws = (char*)d_ws;
    float* t    = (float*)ws;                                   // 25,600,000
    float* h1   = (float*)(ws + 25600000);                      // 25,600,000
    float* dinv = (float*)(ws + 51200000);                      // 200,000
    int*   cnt    = (int*)(ws + 51400000);                      // 200,000
    int*   offs   = (int*)(ws + 51600000);                      // 200,004
    int*   cursor = (int*)(ws + 51800016);                      // 200,000
    int*   srcIdx = (int*)(ws + 52000016);                      // 2,560,000
    int*   gstart = (int*)(ws + 54560016);                      // 1,028
    int*   bsum   = (int*)(ws + 54561056);                      // 196
    int*   boff   = (int*)(ws + 54561264);                      // 196
    unsigned short* wt1 = (unsigned short*)(ws + 54561472);     // 131,072

    const int TB = 256;
    hipMemsetAsync(cnt, 0, N_NODES * sizeof(int), stream);
    k_count<<<(N_EDGES + TB - 1) / TB, TB, 0, stream>>>(col, cnt);
    k_scan_a<<<SCAN_BLOCKS, 256, 0, stream>>>(cnt, offs, bsum);
    k_scan_b<<<1, 64, 0, stream>>>(bsum, boff);
    k_scan_c<<<SCAN_BLOCKS, 256, 0, stream>>>(cnt, boff, offs, cursor, dinv);
    k_fill<<<(N_EDGES + TB - 1) / TB, TB, 0, stream>>>(row, col, cursor, srcIdx);
    k_gstart<<<(N_NODES + TB - 1) / TB, TB, 0, stream>>>(batch, gstart);
    k_cvt_wt<IN_FEATS><<<(IN_FEATS * 128 + TB - 1) / TB, TB, 0, stream>>>(W1, wt1);

    const int GB = (N_NODES + 63) / 64;   // 782
    // layer 1 (bf16 MFMA)
    k_gemm_mfma<IN_FEATS><<<GB, 256, 0, stream>>>(x, wt1, t, N_NODES);
    k_agg<<<N_NODES, 128, 0, stream>>>(t, offs, srcIdx, dinv, b1, h1, 1);
    // layer 2 (fp32 vector)
    k_gemm<HID><<<GB, 256, 0, stream>>>(h1, W2, t, N_NODES);
    k_agg<<<N_NODES, 128, 0, stream>>>(t, offs, srcIdx, dinv, b2, out_h, 0);
    // pool
    k_pool<<<N_GRAPHS, 128, 0, stream>>>(out_h, gstart, out_hs);
}

// Round 4
// 375.813 us; speedup vs baseline: 1.7856x; 1.3119x over previous
//
#include <hip/hip_runtime.h>
#include <hip/hip_bf16.h>

#define N_NODES  50000
#define N_EDGES  640000
#define IN_FEATS 512
#define HID      128
#define OUT_FEATS 128
#define N_GRAPHS 256

#define SCAN_CHUNK 1024
#define SCAN_BLOCKS ((N_NODES + SCAN_CHUNK - 1) / SCAN_CHUNK)   // 49

typedef __attribute__((ext_vector_type(8))) short short8;
typedef __attribute__((ext_vector_type(4))) float f32x4;

__device__ __forceinline__ float bf2f(unsigned short u) {
    return __uint_as_float(((unsigned)u) << 16);
}
__device__ __forceinline__ unsigned short f2bf(float f) {
    __hip_bfloat16 h = __float2bfloat16(f);
    return *(unsigned short*)&h;
}

// ---------------- CSR build ----------------

__global__ void k_count(const int* __restrict__ col, int* __restrict__ cnt) {
    int e = blockIdx.x * blockDim.x + threadIdx.x;
    if (e < N_EDGES) atomicAdd(&cnt[col[e]], 1);
}

__global__ __launch_bounds__(256) void k_scan_a(const int* __restrict__ cnt,
                                                int* __restrict__ offs,
                                                int* __restrict__ bsum) {
    __shared__ int sums[256];
    int t = threadIdx.x;
    int base = blockIdx.x * SCAN_CHUNK + t * 4;
    int c0 = 0, c1 = 0, c2 = 0, c3 = 0;
    if (base + 3 < N_NODES) {
        int4 v = *(const int4*)(cnt + base);
        c0 = v.x; c1 = v.y; c2 = v.z; c3 = v.w;
    } else {
        if (base + 0 < N_NODES) c0 = cnt[base + 0];
        if (base + 1 < N_NODES) c1 = cnt[base + 1];
        if (base + 2 < N_NODES) c2 = cnt[base + 2];
    }
    int ts = c0 + c1 + c2 + c3;
    sums[t] = ts;
    __syncthreads();
#pragma unroll
    for (int off = 1; off < 256; off <<= 1) {
        int add = (t >= off) ? sums[t - off] : 0;
        __syncthreads();
        sums[t] += add;
        __syncthreads();
    }
    int ex = sums[t] - ts;
    if (base + 3 < N_NODES) {
        int4 o;
        o.x = ex; o.y = ex + c0; o.z = ex + c0 + c1; o.w = ex + c0 + c1 + c2;
        *(int4*)(offs + base) = o;
    } else {
        if (base + 0 < N_NODES) offs[base + 0] = ex;
        if (base + 1 < N_NODES) offs[base + 1] = ex + c0;
        if (base + 2 < N_NODES) offs[base + 2] = ex + c0 + c1;
    }
    if (t == 255) bsum[blockIdx.x] = sums[255];
}

__global__ void k_scan_b(int* __restrict__ bsum, int* __restrict__ boff) {
    __shared__ int s[64];
    int t = threadIdx.x;
    int v = (t < SCAN_BLOCKS) ? bsum[t] : 0;
    s[t] = v;
    __syncthreads();
#pragma unroll
    for (int off = 1; off < 64; off <<= 1) {
        int add = (t >= off) ? s[t - off] : 0;
        __syncthreads();
        s[t] += add;
        __syncthreads();
    }
    if (t < SCAN_BLOCKS) boff[t] = s[t] - v;
}

__global__ __launch_bounds__(256) void k_scan_c(const int* __restrict__ cnt,
                                                const int* __restrict__ boff,
                                                int* __restrict__ offs,
                                                int* __restrict__ cursor,
                                                float* __restrict__ dinv) {
    int t = threadIdx.x;
    int b = blockIdx.x;
    int add = boff[b];
    int base = b * SCAN_CHUNK + t * 4;
    if (base + 3 < N_NODES) {
        int4 o = *(const int4*)(offs + base);
        o.x += add; o.y += add; o.z += add; o.w += add;
        *(int4*)(offs + base) = o;
        *(int4*)(cursor + base) = o;
        int4 c = *(const int4*)(cnt + base);
        float4 d;
        d.x = rsqrtf((float)c.x + 1.0f);
        d.y = rsqrtf((float)c.y + 1.0f);
        d.z = rsqrtf((float)c.z + 1.0f);
        d.w = rsqrtf((float)c.w + 1.0f);
        *(float4*)(dinv + base) = d;
    } else {
#pragma unroll
        for (int j = 0; j < 4; ++j) {
            int i = base + j;
            if (i < N_NODES) {
                int o = offs[i] + add;
                offs[i] = o; cursor[i] = o;
                dinv[i] = rsqrtf((float)cnt[i] + 1.0f);
            }
        }
    }
    if (b == 0 && t == 0) offs[N_NODES] = N_EDGES;
}

__global__ void k_fill(const int* __restrict__ row, const int* __restrict__ col,
                       int* __restrict__ cursor, int* __restrict__ srcIdx) {
    int e = blockIdx.x * blockDim.x + threadIdx.x;
    if (e < N_EDGES) {
        int c = col[e];
        int p = atomicAdd(&cursor[c], 1);
        srcIdx[p] = row[e];
    }
}

// ---------------- W transpose+convert: Wt[n][k] = bf16(W[k][n]) ----------------

template <int K>
__global__ void k_cvt_wt(const float* __restrict__ W, unsigned short* __restrict__ Wt) {
    int idx = blockIdx.x * blockDim.x + threadIdx.x;
    if (idx >= K * 128) return;
    int n = idx & 127;
    int k = idx >> 7;
    Wt[(size_t)n * K + k] = f2bf(W[(size_t)k * 128 + n]);
}

// ------- MFMA GEMM (A fp32): Cb[M,128]bf16 = A[M,K]fp32 @ Bt[128][K]bf16^T -------
// BM=64, BN=128, BK=32; 256 thr = 4 waves

template <int K>
__global__ __launch_bounds__(256) void k_gemm_mfma_f32a(const float* __restrict__ A,
                                                        const unsigned short* __restrict__ Bt,
                                                        unsigned short* __restrict__ Cb, int M) {
    __shared__ unsigned short As[4][64][8];
    __shared__ unsigned short Bs[4][128][8];
    int tid = threadIdx.x;
    int wave = tid >> 6;
    int lane = tid & 63;
    int quad = lane >> 4;
    int l15 = lane & 15;
    int m0 = blockIdx.x * 64;

    f32x4 acc[8];
#pragma unroll
    for (int nt = 0; nt < 8; ++nt) acc[nt] = (f32x4){0.f, 0.f, 0.f, 0.f};

    int gm_a = m0 + lane; if (gm_a >= M) gm_a = M - 1;
    const float* ap_base = A + (size_t)gm_a * K + wave * 8;

    for (int k0 = 0; k0 < K; k0 += 32) {
        {
            const float* ap = ap_base + k0;
            float4 v0 = *(const float4*)ap;
            float4 v1 = *(const float4*)(ap + 4);
            float f[8] = {v0.x, v0.y, v0.z, v0.w, v1.x, v1.y, v1.z, v1.w};
            short8 pk;
#pragma unroll
            for (int j = 0; j < 8; ++j) pk[j] = (short)f2bf(f[j]);
            *(short8*)&As[wave][lane][0] = pk;
        }
#pragma unroll
        for (int i = 0; i < 2; ++i) {
            int slot = tid + i * 256;
            int bkq = slot >> 7;
            int n = slot & 127;
            short8 bv = *(const short8*)(Bt + (size_t)n * K + k0 + bkq * 8);
            *(short8*)&Bs[bkq][n][0] = bv;
        }
        __syncthreads();
        short8 a = *(short8*)&As[quad][wave * 16 + l15][0];
#pragma unroll
        for (int nt = 0; nt < 8; ++nt) {
            short8 b = *(short8*)&Bs[quad][nt * 16 + l15][0];
            acc[nt] = __builtin_amdgcn_mfma_f32_16x16x32_bf16(a, b, acc[nt], 0, 0, 0);
        }
        __syncthreads();
    }
    int row_base = m0 + wave * 16 + quad * 4;
#pragma unroll
    for (int nt = 0; nt < 8; ++nt) {
#pragma unroll
        for (int r2 = 0; r2 < 4; ++r2) {
            int gm = row_base + r2;
            if (gm < M) Cb[(size_t)gm * 128 + nt * 16 + l15] = f2bf(acc[nt][r2]);
        }
    }
}

// ------- MFMA GEMM (A bf16): Cb[M,128]bf16 = A[M,K]bf16 @ Bt[128][K]bf16^T -------

template <int K>
__global__ __launch_bounds__(256) void k_gemm_mfma_bf16a(const unsigned short* __restrict__ A,
                                                         const unsigned short* __restrict__ Bt,
                                                         unsigned short* __restrict__ Cb, int M) {
    __shared__ unsigned short As[4][64][8];
    __shared__ unsigned short Bs[4][128][8];
    int tid = threadIdx.x;
    int wave = tid >> 6;
    int lane = tid & 63;
    int quad = lane >> 4;
    int l15 = lane & 15;
    int m0 = blockIdx.x * 64;

    f32x4 acc[8];
#pragma unroll
    for (int nt = 0; nt < 8; ++nt) acc[nt] = (f32x4){0.f, 0.f, 0.f, 0.f};

    int gm_a = m0 + lane; if (gm_a >= M) gm_a = M - 1;
    const unsigned short* ap_base = A + (size_t)gm_a * K + wave * 8;

    for (int k0 = 0; k0 < K; k0 += 32) {
        *(short8*)&As[wave][lane][0] = *(const short8*)(ap_base + k0);
#pragma unroll
        for (int i = 0; i < 2; ++i) {
            int slot = tid + i * 256;
            int bkq = slot >> 7;
            int n = slot & 127;
            *(short8*)&Bs[bkq][n][0] = *(const short8*)(Bt + (size_t)n * K + k0 + bkq * 8);
        }
        __syncthreads();
        short8 a = *(short8*)&As[quad][wave * 16 + l15][0];
#pragma unroll
        for (int nt = 0; nt < 8; ++nt) {
            short8 b = *(short8*)&Bs[quad][nt * 16 + l15][0];
            acc[nt] = __builtin_amdgcn_mfma_f32_16x16x32_bf16(a, b, acc[nt], 0, 0, 0);
        }
        __syncthreads();
    }
    int row_base = m0 + wave * 16 + quad * 4;
#pragma unroll
    for (int nt = 0; nt < 8; ++nt) {
#pragma unroll
        for (int r2 = 0; r2 < 4; ++r2) {
            int gm = row_base + r2;
            if (gm < M) Cb[(size_t)gm * 128 + nt * 16 + l15] = f2bf(acc[nt][r2]);
        }
    }
}

// ---------------- aggregation: one block (128 thr) per node, bf16 gather ----------------
// OUTBF=1: write bf16 (+ReLU); OUTBF=0: write fp32

template <int RELU, int OUTBF>
__global__ __launch_bounds__(128) void k_agg(const unsigned short* __restrict__ t,
                                             const int* __restrict__ offs,
                                             const int* __restrict__ srcIdx,
                                             const float* __restrict__ dinv,
                                             const float* __restrict__ bias,
                                             void* __restrict__ out_) {
    int i = blockIdx.x;
    int f = threadIdx.x;
    float di = dinv[i];
    float s = bf2f(t[(size_t)i * 128 + f]) * di;
    int lo = offs[i], hi = offs[i + 1];
    int e = lo;
    for (; e + 4 <= hi; e += 4) {
        int s0 = srcIdx[e + 0], s1 = srcIdx[e + 1], s2 = srcIdx[e + 2], s3 = srcIdx[e + 3];
        float d0 = dinv[s0], d1 = dinv[s1], d2 = dinv[s2], d3 = dinv[s3];
        float v0 = bf2f(t[(size_t)s0 * 128 + f]);
        float v1 = bf2f(t[(size_t)s1 * 128 + f]);
        float v2 = bf2f(t[(size_t)s2 * 128 + f]);
        float v3 = bf2f(t[(size_t)s3 * 128 + f]);
        s = fmaf(v0, d0, s); s = fmaf(v1, d1, s);
        s = fmaf(v2, d2, s); s = fmaf(v3, d3, s);
    }
    for (; e < hi; ++e) {
        int sn = srcIdx[e];
        s = fmaf(bf2f(t[(size_t)sn * 128 + f]), dinv[sn], s);
    }
    float v = s * di + bias[f];
    if (RELU) v = fmaxf(v, 0.f);
    if (OUTBF) ((unsigned short*)out_)[(size_t)i * 128 + f] = f2bf(v);
    else       ((float*)out_)[(size_t)i * 128 + f] = v;
}

// ---------------- global add pool (4 blocks per graph, atomic combine) ----------------

__global__ void k_gstart(const int* __restrict__ batch, int* __restrict__ gstart) {
    int i = blockIdx.x * blockDim.x + threadIdx.x;
    if (i >= N_NODES) return;
    int b = batch[i];
    int bp = (i == 0) ? -1 : batch[i - 1];
    for (int g = bp + 1; g <= b; ++g) gstart[g] = i;
    if (i == N_NODES - 1) {
        for (int g = b + 1; g <= N_GRAPHS; ++g) gstart[g] = N_NODES;
    }
}

__global__ __launch_bounds__(128) void k_pool(const float* __restrict__ h,
                                              const int* __restrict__ gstart,
                                              float* __restrict__ hs) {
    int g = blockIdx.x >> 2;
    int c = blockIdx.x & 3;
    int f = threadIdx.x;
    int lo = gstart[g], hi = gstart[g + 1];
    int len = hi - lo;
    int chunk = (len + 3) >> 2;
    int r0 = lo + c * chunk;
    int r1 = r0 + chunk; if (r1 > hi) r1 = hi;
    if (r0 >= r1) return;
    float s = 0.f;
    for (int r = r0; r < r1; ++r) s += h[(size_t)r * 128 + f];
    atomicAdd(&hs[(size_t)g * 128 + f], s);
}

// ---------------- launch ----------------

extern "C" void kernel_launch(void* const* d_in, const int* in_sizes, int n_in,
                              void* d_out, int out_size, void* d_ws, size_t ws_size,
                              hipStream_t stream) {
    const float* x  = (const float*)d_in[0];
    const float* W1 = (const float*)d_in[1];
    const float* b1 = (const float*)d_in[2];
    const float* W2 = (const float*)d_in[3];
    const float* b2 = (const float*)d_in[4];
    const int*   ei = (const int*)d_in[5];
    const int*   batch = (const int*)d_in[6];
    const int* row = ei;
    const int* col = ei + N_EDGES;

    float* out_hs = (float*)d_out;
    float* out_h  = (float*)d_out + N_GRAPHS * OUT_FEATS;

    // workspace layout (16B-aligned)
    char* ws = (char*)d_ws;
    unsigned short* tb   = (unsigned short*)ws;                  // 12,800,000
    unsigned short* h1b  = (unsigned short*)(ws + 12800000);     // 12,800,000
    unsigned short* tb2  = (unsigned short*)(ws + 25600000);     // 12,800,000
    float* dinv = (float*)(ws + 38400000);                       // 200,000
    int*   cnt    = (int*)(ws + 38600000);                       // 200,000
    int*   offs   = (int*)(ws + 38800000);                       // 200,016
    int*   cursor = (int*)(ws + 39000016);                       // 200,000
    int*   srcIdx = (int*)(ws + 39200016);                       // 2,560,000
    int*   gstart = (int*)(ws + 41760016);                       // 1,040
    int*   bsum   = (int*)(ws + 41761056);                       // 208
    int*   boff   = (int*)(ws + 41761264);                       // 208
    unsigned short* wt1 = (unsigned short*)(ws + 41761472);      // 131,072
    unsigned short* wt2 = (unsigned short*)(ws + 41892544);      // 32,768

    const int TB = 256;
    hipMemsetAsync(cnt, 0, N_NODES * sizeof(int), stream);
    hipMemsetAsync(out_hs, 0, N_GRAPHS * OUT_FEATS * sizeof(float), stream);
    k_count<<<(N_EDGES + TB - 1) / TB, TB, 0, stream>>>(col, cnt);
    k_scan_a<<<SCAN_BLOCKS, 256, 0, stream>>>(cnt, offs, bsum);
    k_scan_b<<<1, 64, 0, stream>>>(bsum, boff);
    k_scan_c<<<SCAN_BLOCKS, 256, 0, stream>>>(cnt, boff, offs, cursor, dinv);
    k_fill<<<(N_EDGES + TB - 1) / TB, TB, 0, stream>>>(row, col, cursor, srcIdx);
    k_gstart<<<(N_NODES + TB - 1) / TB, TB, 0, stream>>>(batch, gstart);
    k_cvt_wt<IN_FEATS><<<(IN_FEATS * 128 + TB - 1) / TB, TB, 0, stream>>>(W1, wt1);
    k_cvt_wt<HID><<<(HID * 128 + TB - 1) / TB, TB, 0, stream>>>(W2, wt2);

    const int GB = (N_NODES + 63) / 64;   // 782
    // layer 1: bf16 MFMA, bf16 t
    k_gemm_mfma_f32a<IN_FEATS><<<GB, 256, 0, stream>>>(x, wt1, tb, N_NODES);
    k_agg<1, 1><<<N_NODES, 128, 0, stream>>>(tb, offs, srcIdx, dinv, b1, h1b);
    // layer 2: bf16 MFMA on bf16 h1
    k_gemm_mfma_bf16a<HID><<<GB, 256, 0, stream>>>(h1b, wt2, tb2, N_NODES);
    k_agg<0, 0><<<N_NODES, 128, 0, stream>>>(tb2, offs, srcIdx, dinv, b2, out_h);
    // pool (hs zeroed above)
    k_pool<<<N_GRAPHS * 4, 128, 0, stream>>>(out_h, gstart, out_hs);
}

// Round 5
// 351.528 us; speedup vs baseline: 1.9089x; 1.0691x over previous
//
#include <hip/hip_runtime.h>
#include <hip/hip_bf16.h>

#define N_NODES  50000
#define N_EDGES  640000
#define IN_FEATS 512
#define HID      128
#define OUT_FEATS 128
#define N_GRAPHS 256

#define SCAN_CHUNK 1024
#define SCAN_BLOCKS ((N_NODES + SCAN_CHUNK - 1) / SCAN_CHUNK)   // 49

typedef __attribute__((ext_vector_type(8))) short short8;
typedef __attribute__((ext_vector_type(4))) float f32x4;

__device__ __forceinline__ float bf2f(unsigned u16) {
    return __uint_as_float(u16 << 16);
}
__device__ __forceinline__ unsigned short f2bf(float f) {
    __hip_bfloat16 h = __float2bfloat16(f);
    return *(unsigned short*)&h;
}

// ---------------- fused preprocessing: gstart | zero cnt | cvt W1 | cvt W2 | zero hs ----
// block ranges: [0,196) gstart, [196,392) zero cnt, [392,648) cvt1, [648,712) cvt2,
//               [712,840) zero hs

#define PREP_BLOCKS 840

__global__ __launch_bounds__(256) void k_prep(const float* __restrict__ W1,
                                              const float* __restrict__ W2,
                                              const int* __restrict__ batch,
                                              unsigned short* __restrict__ wt1,
                                              unsigned short* __restrict__ wt2,
                                              int* __restrict__ cnt,
                                              int* __restrict__ gstart,
                                              float* __restrict__ hs) {
    int b = blockIdx.x;
    int t = threadIdx.x;
    if (b < 196) {
        int i = b * 256 + t;
        if (i < N_NODES) {
            int bt = batch[i];
            int bp = (i == 0) ? -1 : batch[i - 1];
            for (int g = bp + 1; g <= bt; ++g) gstart[g] = i;
            if (i == N_NODES - 1)
                for (int g = bt + 1; g <= N_GRAPHS; ++g) gstart[g] = N_NODES;
        }
    } else if (b < 392) {
        int i = (b - 196) * 256 + t;
        if (i < N_NODES) cnt[i] = 0;
    } else if (b < 648) {
        int idx = (b - 392) * 256 + t;           // 512*128 total
        int n = idx & 127, k = idx >> 7;
        wt1[(size_t)n * IN_FEATS + k] = f2bf(W1[(size_t)k * 128 + n]);
    } else if (b < 712) {
        int idx = (b - 648) * 256 + t;           // 128*128 total
        int n = idx & 127, k = idx >> 7;
        wt2[(size_t)n * HID + k] = f2bf(W2[(size_t)k * 128 + n]);
    } else {
        int idx = (b - 712) * 256 + t;           // 256*128 floats
        hs[idx] = 0.f;
    }
}

// ---------------- CSR build ----------------

__global__ void k_count(const int* __restrict__ col, int* __restrict__ cnt) {
    int e = blockIdx.x * blockDim.x + threadIdx.x;
    if (e < N_EDGES) atomicAdd(&cnt[col[e]], 1);
}

__global__ __launch_bounds__(256) void k_scan_a(const int* __restrict__ cnt,
                                                int* __restrict__ offs,
                                                int* __restrict__ bsum) {
    __shared__ int sums[256];
    int t = threadIdx.x;
    int base = blockIdx.x * SCAN_CHUNK + t * 4;
    int c0 = 0, c1 = 0, c2 = 0, c3 = 0;
    if (base + 3 < N_NODES) {
        int4 v = *(const int4*)(cnt + base);
        c0 = v.x; c1 = v.y; c2 = v.z; c3 = v.w;
    } else {
        if (base + 0 < N_NODES) c0 = cnt[base + 0];
        if (base + 1 < N_NODES) c1 = cnt[base + 1];
        if (base + 2 < N_NODES) c2 = cnt[base + 2];
    }
    int ts = c0 + c1 + c2 + c3;
    sums[t] = ts;
    __syncthreads();
#pragma unroll
    for (int off = 1; off < 256; off <<= 1) {
        int add = (t >= off) ? sums[t - off] : 0;
        __syncthreads();
        sums[t] += add;
        __syncthreads();
    }
    int ex = sums[t] - ts;
    if (base + 3 < N_NODES) {
        int4 o;
        o.x = ex; o.y = ex + c0; o.z = ex + c0 + c1; o.w = ex + c0 + c1 + c2;
        *(int4*)(offs + base) = o;
    } else {
        if (base + 0 < N_NODES) offs[base + 0] = ex;
        if (base + 1 < N_NODES) offs[base + 1] = ex + c0;
        if (base + 2 < N_NODES) offs[base + 2] = ex + c0 + c1;
    }
    if (t == 255) bsum[blockIdx.x] = sums[255];
}

// scan_c absorbs scan_b: every block scans the 49 block sums in LDS
__global__ __launch_bounds__(256) void k_scan_c(const int* __restrict__ cnt,
                                                const int* __restrict__ bsum,
                                                int* __restrict__ offs,
                                                int* __restrict__ cursor,
                                                float* __restrict__ dinv) {
    __shared__ int sb[64];
    int t = threadIdx.x;
    int b = blockIdx.x;
    if (t < 64) sb[t] = (t < SCAN_BLOCKS) ? bsum[t] : 0;
    __syncthreads();
#pragma unroll
    for (int off = 1; off < 64; off <<= 1) {
        int add = 0;
        if (t < 64 && t >= off) add = sb[t - off];
        __syncthreads();
        if (t < 64) sb[t] += add;
        __syncthreads();
    }
    int add = (b == 0) ? 0 : sb[b - 1];   // exclusive block offset
    int base = b * SCAN_CHUNK + t * 4;
    if (base + 3 < N_NODES) {
        int4 o = *(const int4*)(offs + base);
        o.x += add; o.y += add; o.z += add; o.w += add;
        *(int4*)(offs + base) = o;
        *(int4*)(cursor + base) = o;
        int4 c = *(const int4*)(cnt + base);
        float4 d;
        d.x = rsqrtf((float)c.x + 1.0f);
        d.y = rsqrtf((float)c.y + 1.0f);
        d.z = rsqrtf((float)c.z + 1.0f);
        d.w = rsqrtf((float)c.w + 1.0f);
        *(float4*)(dinv + base) = d;
    } else {
#pragma unroll
        for (int j = 0; j < 4; ++j) {
            int i = base + j;
            if (i < N_NODES) {
                int o = offs[i] + add;
                offs[i] = o; cursor[i] = o;
                dinv[i] = rsqrtf((float)cnt[i] + 1.0f);
            }
        }
    }
    if (b == 0 && t == 0) offs[N_NODES] = N_EDGES;
}

__global__ void k_fill(const int* __restrict__ row, const int* __restrict__ col,
                       int* __restrict__ cursor, int* __restrict__ srcIdx) {
    int e = blockIdx.x * blockDim.x + threadIdx.x;
    if (e < N_EDGES) {
        int c = col[e];
        int p = atomicAdd(&cursor[c], 1);
        srcIdx[p] = row[e];
    }
}

// ------- MFMA GEMM (A fp32): Cb[M,128]bf16 = A[M,K]fp32 @ Bt[128][K]bf16^T -------

template <int K>
__global__ __launch_bounds__(256) void k_gemm_mfma_f32a(const float* __restrict__ A,
                                                        const unsigned short* __restrict__ Bt,
                                                        unsigned short* __restrict__ Cb, int M) {
    __shared__ unsigned short As[4][64][8];
    __shared__ unsigned short Bs[4][128][8];
    int tid = threadIdx.x;
    int wave = tid >> 6;
    int lane = tid & 63;
    int quad = lane >> 4;
    int l15 = lane & 15;
    int m0 = blockIdx.x * 64;

    f32x4 acc[8];
#pragma unroll
    for (int nt = 0; nt < 8; ++nt) acc[nt] = (f32x4){0.f, 0.f, 0.f, 0.f};

    int gm_a = m0 + lane; if (gm_a >= M) gm_a = M - 1;
    const float* ap_base = A + (size_t)gm_a * K + wave * 8;

    for (int k0 = 0; k0 < K; k0 += 32) {
        {
            const float* ap = ap_base + k0;
            float4 v0 = *(const float4*)ap;
            float4 v1 = *(const float4*)(ap + 4);
            float f[8] = {v0.x, v0.y, v0.z, v0.w, v1.x, v1.y, v1.z, v1.w};
            short8 pk;
#pragma unroll
            for (int j = 0; j < 8; ++j) pk[j] = (short)f2bf(f[j]);
            *(short8*)&As[wave][lane][0] = pk;
        }
#pragma unroll
        for (int i = 0; i < 2; ++i) {
            int slot = tid + i * 256;
            int bkq = slot >> 7;
            int n = slot & 127;
            *(short8*)&Bs[bkq][n][0] = *(const short8*)(Bt + (size_t)n * K + k0 + bkq * 8);
        }
        __syncthreads();
        short8 a = *(short8*)&As[quad][wave * 16 + l15][0];
#pragma unroll
        for (int nt = 0; nt < 8; ++nt) {
            short8 b = *(short8*)&Bs[quad][nt * 16 + l15][0];
            acc[nt] = __builtin_amdgcn_mfma_f32_16x16x32_bf16(a, b, acc[nt], 0, 0, 0);
        }
        __syncthreads();
    }
    int row_base = m0 + wave * 16 + quad * 4;
#pragma unroll
    for (int nt = 0; nt < 8; ++nt) {
#pragma unroll
        for (int r2 = 0; r2 < 4; ++r2) {
            int gm = row_base + r2;
            if (gm < M) Cb[(size_t)gm * 128 + nt * 16 + l15] = f2bf(acc[nt][r2]);
        }
    }
}

// ------- MFMA GEMM (A bf16) -------

template <int K>
__global__ __launch_bounds__(256) void k_gemm_mfma_bf16a(const unsigned short* __restrict__ A,
                                                         const unsigned short* __restrict__ Bt,
                                                         unsigned short* __restrict__ Cb, int M) {
    __shared__ unsigned short As[4][64][8];
    __shared__ unsigned short Bs[4][128][8];
    int tid = threadIdx.x;
    int wave = tid >> 6;
    int lane = tid & 63;
    int quad = lane >> 4;
    int l15 = lane & 15;
    int m0 = blockIdx.x * 64;

    f32x4 acc[8];
#pragma unroll
    for (int nt = 0; nt < 8; ++nt) acc[nt] = (f32x4){0.f, 0.f, 0.f, 0.f};

    int gm_a = m0 + lane; if (gm_a >= M) gm_a = M - 1;
    const unsigned short* ap_base = A + (size_t)gm_a * K + wave * 8;

    for (int k0 = 0; k0 < K; k0 += 32) {
        *(short8*)&As[wave][lane][0] = *(const short8*)(ap_base + k0);
#pragma unroll
        for (int i = 0; i < 2; ++i) {
            int slot = tid + i * 256;
            int bkq = slot >> 7;
            int n = slot & 127;
            *(short8*)&Bs[bkq][n][0] = *(const short8*)(Bt + (size_t)n * K + k0 + bkq * 8);
        }
        __syncthreads();
        short8 a = *(short8*)&As[quad][wave * 16 + l15][0];
#pragma unroll
        for (int nt = 0; nt < 8; ++nt) {
            short8 b = *(short8*)&Bs[quad][nt * 16 + l15][0];
            acc[nt] = __builtin_amdgcn_mfma_f32_16x16x32_bf16(a, b, acc[nt], 0, 0, 0);
        }
        __syncthreads();
    }
    int row_base = m0 + wave * 16 + quad * 4;
#pragma unroll
    for (int nt = 0; nt < 8; ++nt) {
#pragma unroll
        for (int r2 = 0; r2 < 4; ++r2) {
            int gm = row_base + r2;
            if (gm < M) Cb[(size_t)gm * 128 + nt * 16 + l15] = f2bf(acc[nt][r2]);
        }
    }
}

// ---------------- aggregation: one WAVE per node, packed bf16x2 per lane ----------------
// t is uint-packed bf16 rows [node][64]; unroll-8 edge loop for MLP.

template <int RELU, int OUTBF>
__global__ __launch_bounds__(128) void k_agg(const unsigned* __restrict__ t,
                                             const int* __restrict__ offs,
                                             const int* __restrict__ srcIdx,
                                             const float* __restrict__ dinv,
                                             const float* __restrict__ bias,
                                             void* __restrict__ out_) {
    int wave = threadIdx.x >> 6;
    int lane = threadIdx.x & 63;
    int i = blockIdx.x * 2 + wave;     // N_NODES even; always < N_NODES
    float di = dinv[i];
    unsigned self = t[(size_t)i * 64 + lane];
    float s0 = bf2f(self & 0xffffu) * di;
    float s1 = bf2f(self >> 16) * di;
    int lo = offs[i], hi = offs[i + 1];
    int e = lo;
    for (; e + 8 <= hi; e += 8) {
        int idx[8];
#pragma unroll
        for (int j = 0; j < 8; ++j) idx[j] = srcIdx[e + j];
        unsigned v[8];
#pragma unroll
        for (int j = 0; j < 8; ++j) v[j] = t[(size_t)idx[j] * 64 + lane];
        float d[8];
#pragma unroll
        for (int j = 0; j < 8; ++j) d[j] = dinv[idx[j]];
#pragma unroll
        for (int j = 0; j < 8; ++j) {
            s0 = fmaf(bf2f(v[j] & 0xffffu), d[j], s0);
            s1 = fmaf(bf2f(v[j] >> 16), d[j], s1);
        }
    }
    for (; e < hi; ++e) {
        int sn = srcIdx[e];
        unsigned vv = t[(size_t)sn * 64 + lane];
        float dd = dinv[sn];
        s0 = fmaf(bf2f(vv & 0xffffu), dd, s0);
        s1 = fmaf(bf2f(vv >> 16), dd, s1);
    }
    float2 bb = *(const float2*)(bias + lane * 2);
    float r0 = s0 * di + bb.x;
    float r1 = s1 * di + bb.y;
    if (RELU) { r0 = fmaxf(r0, 0.f); r1 = fmaxf(r1, 0.f); }
    if (OUTBF) {
        unsigned o = (unsigned)f2bf(r0) | ((unsigned)f2bf(r1) << 16);
        ((unsigned*)out_)[(size_t)i * 64 + lane] = o;
    } else {
        *(float2*)((float*)out_ + (size_t)i * 128 + lane * 2) = make_float2(r0, r1);
    }
}

// ---------------- global add pool (4 blocks per graph, atomic combine) ----------------

__global__ __launch_bounds__(128) void k_pool(const float* __restrict__ h,
                                              const int* __restrict__ gstart,
                                              float* __restrict__ hs) {
    int g = blockIdx.x >> 2;
    int c = blockIdx.x & 3;
    int f = threadIdx.x;
    int lo = gstart[g], hi = gstart[g + 1];
    int len = hi - lo;
    int chunk = (len + 3) >> 2;
    int r0 = lo + c * chunk;
    int r1 = r0 + chunk; if (r1 > hi) r1 = hi;
    if (r0 >= r1) return;
    float s = 0.f;
    for (int r = r0; r < r1; ++r) s += h[(size_t)r * 128 + f];
    atomicAdd(&hs[(size_t)g * 128 + f], s);
}

// ---------------- launch ----------------

extern "C" void kernel_launch(void* const* d_in, const int* in_sizes, int n_in,
                              void* d_out, int out_size, void* d_ws, size_t ws_size,
                              hipStream_t stream) {
    const float* x  = (const float*)d_in[0];
    const float* W1 = (const float*)d_in[1];
    const float* b1 = (const float*)d_in[2];
    const float* W2 = (const float*)d_in[3];
    const float* b2 = (const float*)d_in[4];
    const int*   ei = (const int*)d_in[5];
    const int*   batch = (const int*)d_in[6];
    const int* row = ei;
    const int* col = ei + N_EDGES;

    float* out_hs = (float*)d_out;
    float* out_h  = (float*)d_out + N_GRAPHS * OUT_FEATS;

    // workspace layout (16B-aligned)
    char* ws = (char*)d_ws;
    unsigned short* tb   = (unsigned short*)ws;                  // 12,800,000
    unsigned short* h1b  = (unsigned short*)(ws + 12800000);     // 12,800,000
    unsigned short* tb2  = (unsigned short*)(ws + 25600000);     // 12,800,000
    float* dinv = (float*)(ws + 38400000);                       // 200,000
    int*   cnt    = (int*)(ws + 38600000);                       // 200,000
    int*   offs   = (int*)(ws + 38800000);                       // 200,016
    int*   cursor = (int*)(ws + 39000016);                       // 200,000
    int*   srcIdx = (int*)(ws + 39200016);                       // 2,560,000
    int*   gstart = (int*)(ws + 41760016);                       // 1,040
    int*   bsum   = (int*)(ws + 41761056);                       // 208
    unsigned short* wt1 = (unsigned short*)(ws + 41761472);      // 131,072
    unsigned short* wt2 = (unsigned short*)(ws + 41892544);      // 32,768

    const int TB = 256;
    // fused preprocessing (zero cnt/hs, gstart, weight cvt)
    k_prep<<<PREP_BLOCKS, 256, 0, stream>>>(W1, W2, batch, wt1, wt2, cnt, gstart, out_hs);
    // CSR build
    k_count<<<(N_EDGES + TB - 1) / TB, TB, 0, stream>>>(col, cnt);
    k_scan_a<<<SCAN_BLOCKS, 256, 0, stream>>>(cnt, offs, bsum);
    k_scan_c<<<SCAN_BLOCKS, 256, 0, stream>>>(cnt, bsum, offs, cursor, dinv);
    k_fill<<<(N_EDGES + TB - 1) / TB, TB, 0, stream>>>(row, col, cursor, srcIdx);

    const int GB = (N_NODES + 63) / 64;   // 782
    // layer 1
    k_gemm_mfma_f32a<IN_FEATS><<<GB, 256, 0, stream>>>(x, wt1, tb, N_NODES);
    k_agg<1, 1><<<N_NODES / 2, 128, 0, stream>>>((const unsigned*)tb, offs, srcIdx, dinv, b1, h1b);
    // layer 2
    k_gemm_mfma_bf16a<HID><<<GB, 256, 0, stream>>>(h1b, wt2, tb2, N_NODES);
    k_agg<0, 0><<<N_NODES / 2, 128, 0, stream>>>((const unsigned*)tb2, offs, srcIdx, dinv, b2, out_h);
    // pool
    k_pool<<<N_GRAPHS * 4, 128, 0, stream>>>(out_h, gstart, out_hs);
}

// Round 7
// 345.579 us; speedup vs baseline: 1.9418x; 1.0172x over previous
//
#include <hip/hip_runtime.h>
#include <hip/hip_bf16.h>

#define N_NODES  50000
#define N_EDGES  640000
#define IN_FEATS 512
#define HID      128
#define OUT_FEATS 128
#define N_GRAPHS 256

#define SCAN_CHUNK 1024
#define SCAN_BLOCKS ((N_NODES + SCAN_CHUNK - 1) / SCAN_CHUNK)   // 49

typedef __attribute__((ext_vector_type(8))) short short8;
typedef __attribute__((ext_vector_type(4))) float f32x4;

__device__ __forceinline__ float bf2f(unsigned u16) {
    return __uint_as_float(u16 << 16);
}
__device__ __forceinline__ unsigned short f2bf(float f) {
    __hip_bfloat16 h = __float2bfloat16(f);
    return *(unsigned short*)&h;
}

// ---------------- fused preprocessing: gstart | zero cnt | cvt W1 | cvt W2 | zero hs ----
#define PREP_BLOCKS 840

__global__ __launch_bounds__(256) void k_prep(const float* __restrict__ W1,
                                              const float* __restrict__ W2,
                                              const int* __restrict__ batch,
                                              unsigned short* __restrict__ wt1,
                                              unsigned short* __restrict__ wt2,
                                              int* __restrict__ cnt,
                                              int* __restrict__ gstart,
                                              float* __restrict__ hs) {
    int b = blockIdx.x;
    int t = threadIdx.x;
    if (b < 196) {
        int i = b * 256 + t;
        if (i < N_NODES) {
            int bt = batch[i];
            int bp = (i == 0) ? -1 : batch[i - 1];
            for (int g = bp + 1; g <= bt; ++g) gstart[g] = i;
            if (i == N_NODES - 1)
                for (int g = bt + 1; g <= N_GRAPHS; ++g) gstart[g] = N_NODES;
        }
    } else if (b < 392) {
        int i = (b - 196) * 256 + t;
        if (i < N_NODES) cnt[i] = 0;
    } else if (b < 648) {
        int idx = (b - 392) * 256 + t;
        int n = idx & 127, k = idx >> 7;
        wt1[(size_t)n * IN_FEATS + k] = f2bf(W1[(size_t)k * 128 + n]);
    } else if (b < 712) {
        int idx = (b - 648) * 256 + t;
        int n = idx & 127, k = idx >> 7;
        wt2[(size_t)n * HID + k] = f2bf(W2[(size_t)k * 128 + n]);
    } else {
        int idx = (b - 712) * 256 + t;
        hs[idx] = 0.f;
    }
}

// ---------------- CSR build ----------------

__global__ void k_count(const int* __restrict__ col, int* __restrict__ cnt) {
    int e4 = (blockIdx.x * blockDim.x + threadIdx.x) * 4;   // N_EDGES % 4 == 0
    if (e4 >= N_EDGES) return;
    int4 c = *(const int4*)(col + e4);
    atomicAdd(&cnt[c.x], 1);
    atomicAdd(&cnt[c.y], 1);
    atomicAdd(&cnt[c.z], 1);
    atomicAdd(&cnt[c.w], 1);
}

__global__ __launch_bounds__(256) void k_scan_a(const int* __restrict__ cnt,
                                                int* __restrict__ offs,
                                                int* __restrict__ bsum) {
    __shared__ int sums[256];
    int t = threadIdx.x;
    int base = blockIdx.x * SCAN_CHUNK + t * 4;
    int c0 = 0, c1 = 0, c2 = 0, c3 = 0;
    if (base + 3 < N_NODES) {
        int4 v = *(const int4*)(cnt + base);
        c0 = v.x; c1 = v.y; c2 = v.z; c3 = v.w;
    } else {
        if (base + 0 < N_NODES) c0 = cnt[base + 0];
        if (base + 1 < N_NODES) c1 = cnt[base + 1];
        if (base + 2 < N_NODES) c2 = cnt[base + 2];
    }
    int ts = c0 + c1 + c2 + c3;
    sums[t] = ts;
    __syncthreads();
#pragma unroll
    for (int off = 1; off < 256; off <<= 1) {
        int add = (t >= off) ? sums[t - off] : 0;
        __syncthreads();
        sums[t] += add;
        __syncthreads();
    }
    int ex = sums[t] - ts;
    if (base + 3 < N_NODES) {
        int4 o;
        o.x = ex; o.y = ex + c0; o.z = ex + c0 + c1; o.w = ex + c0 + c1 + c2;
        *(int4*)(offs + base) = o;
    } else {
        if (base + 0 < N_NODES) offs[base + 0] = ex;
        if (base + 1 < N_NODES) offs[base + 1] = ex + c0;
        if (base + 2 < N_NODES) offs[base + 2] = ex + c0 + c1;
    }
    if (t == 255) bsum[blockIdx.x] = sums[255];
}

__global__ __launch_bounds__(256) void k_scan_c(const int* __restrict__ cnt,
                                                const int* __restrict__ bsum,
                                                int* __restrict__ offs,
                                                int* __restrict__ cursor,
                                                float* __restrict__ dinv) {
    __shared__ int sb[64];
    int t = threadIdx.x;
    int b = blockIdx.x;
    if (t < 64) sb[t] = (t < SCAN_BLOCKS) ? bsum[t] : 0;
    __syncthreads();
#pragma unroll
    for (int off = 1; off < 64; off <<= 1) {
        int add = 0;
        if (t < 64 && t >= off) add = sb[t - off];
        __syncthreads();
        if (t < 64) sb[t] += add;
        __syncthreads();
    }
    int add = (b == 0) ? 0 : sb[b - 1];
    int base = b * SCAN_CHUNK + t * 4;
    if (base + 3 < N_NODES) {
        int4 o = *(const int4*)(offs + base);
        o.x += add; o.y += add; o.z += add; o.w += add;
        *(int4*)(offs + base) = o;
        *(int4*)(cursor + base) = o;
        int4 c = *(const int4*)(cnt + base);
        float4 d;
        d.x = rsqrtf((float)c.x + 1.0f);
        d.y = rsqrtf((float)c.y + 1.0f);
        d.z = rsqrtf((float)c.z + 1.0f);
        d.w = rsqrtf((float)c.w + 1.0f);
        *(float4*)(dinv + base) = d;
    } else {
#pragma unroll
        for (int j = 0; j < 4; ++j) {
            int i = base + j;
            if (i < N_NODES) {
                int o = offs[i] + add;
                offs[i] = o; cursor[i] = o;
                dinv[i] = rsqrtf((float)cnt[i] + 1.0f);
            }
        }
    }
    if (b == 0 && t == 0) offs[N_NODES] = N_EDGES;
}

__global__ void k_fill(const int* __restrict__ row, const int* __restrict__ col,
                       int* __restrict__ cursor, int* __restrict__ srcIdx) {
    int e4 = (blockIdx.x * blockDim.x + threadIdx.x) * 4;
    if (e4 >= N_EDGES) return;
    int4 r = *(const int4*)(row + e4);
    int4 c = *(const int4*)(col + e4);
    srcIdx[atomicAdd(&cursor[c.x], 1)] = r.x;
    srcIdx[atomicAdd(&cursor[c.y], 1)] = r.y;
    srcIdx[atomicAdd(&cursor[c.z], 1)] = r.z;
    srcIdx[atomicAdd(&cursor[c.w], 1)] = r.w;
}

// ------- GEMM1 (128x128 tile): Cb[M,128]bf16 = A[M,K]fp32 @ Bt[128][K]bf16^T -------
// 256 thr = 4 waves; wave (w>>1) picks 64-row half, (w&1) picks 64-col half; 4x4 MFMA grid.
// Fragment read: lane's own k-octet is As[quad][...] — ONE fragment set per K=32 step.

template <int K>
__global__ __launch_bounds__(256) void k_gemm1(const float* __restrict__ A,
                                               const unsigned short* __restrict__ Bt,
                                               unsigned short* __restrict__ Cb, int M) {
    __shared__ unsigned short As[4][128][8];   // [kq][row][8k]  8 KB
    __shared__ unsigned short Bs[4][128][8];   // [kq][n][8k]    8 KB
    int tid = threadIdx.x;
    int wave = tid >> 6;
    int lane = tid & 63;
    int quad = lane >> 4;
    int l15 = lane & 15;
    int m0 = blockIdx.x * 128;
    int mw = (wave >> 1) * 64;
    int nw = (wave & 1) * 64;

    f32x4 acc[4][4];
#pragma unroll
    for (int i = 0; i < 4; ++i)
#pragma unroll
        for (int j = 0; j < 4; ++j) acc[i][j] = (f32x4){0.f, 0.f, 0.f, 0.f};

    // A staging: slots tid and tid+256 cover 128 rows x 4 k-octets
    int r0s = tid >> 2, kq0 = tid & 3;
    int r1s = r0s + 64;
    int gm0 = m0 + r0s; if (gm0 >= M) gm0 = M - 1;
    int gm1 = m0 + r1s; if (gm1 >= M) gm1 = M - 1;
    const float* ap0 = A + (size_t)gm0 * K + kq0 * 8;
    const float* ap1 = A + (size_t)gm1 * K + kq0 * 8;

    for (int k0 = 0; k0 < K; k0 += 32) {
        // stage A: 128 rows x 32 k, fp32 -> bf16
        {
            float4 v0 = *(const float4*)(ap0 + k0);
            float4 v1 = *(const float4*)(ap0 + k0 + 4);
            float f[8] = {v0.x, v0.y, v0.z, v0.w, v1.x, v1.y, v1.z, v1.w};
            short8 pk;
#pragma unroll
            for (int j = 0; j < 8; ++j) pk[j] = (short)f2bf(f[j]);
            *(short8*)&As[kq0][r0s][0] = pk;
            v0 = *(const float4*)(ap1 + k0);
            v1 = *(const float4*)(ap1 + k0 + 4);
            float g[8] = {v0.x, v0.y, v0.z, v0.w, v1.x, v1.y, v1.z, v1.w};
#pragma unroll
            for (int j = 0; j < 8; ++j) pk[j] = (short)f2bf(g[j]);
            *(short8*)&As[kq0][r1s][0] = pk;
        }
        // stage B: 128 n x 32 k
#pragma unroll
        for (int i = 0; i < 2; ++i) {
            int slot = tid + i * 256;
            int n = slot >> 2, kq = slot & 3;
            *(short8*)&Bs[kq][n][0] = *(const short8*)(Bt + (size_t)n * K + k0 + kq * 8);
        }
        __syncthreads();
        short8 af[4], bfr[4];
#pragma unroll
        for (int i = 0; i < 4; ++i) af[i] = *(short8*)&As[quad][mw + i * 16 + l15][0];
#pragma unroll
        for (int j = 0; j < 4; ++j) bfr[j] = *(short8*)&Bs[quad][nw + j * 16 + l15][0];
#pragma unroll
        for (int i = 0; i < 4; ++i)
#pragma unroll
            for (int j = 0; j < 4; ++j)
                acc[i][j] = __builtin_amdgcn_mfma_f32_16x16x32_bf16(af[i], bfr[j], acc[i][j], 0, 0, 0);
        __syncthreads();
    }
#pragma unroll
    for (int i = 0; i < 4; ++i) {
        int rb = m0 + mw + i * 16 + quad * 4;
#pragma unroll
        for (int j = 0; j < 4; ++j) {
            int colb = nw + j * 16 + l15;
#pragma unroll
            for (int r2 = 0; r2 < 4; ++r2) {
                int gm = rb + r2;
                if (gm < M) Cb[(size_t)gm * 128 + colb] = f2bf(acc[i][j][r2]);
            }
        }
    }
}

// ------- GEMM2 + bias + fused pool: out[M,128]f32 = G[M,128]bf16 @ Bt^T + b;
//         hs[batch[m]] += out[m]  (rows batch-sorted -> grouped atomics) -------

__global__ __launch_bounds__(256) void k_gemm2_pool(const unsigned short* __restrict__ G,
                                                    const unsigned short* __restrict__ Bt,
                                                    const float* __restrict__ bias,
                                                    const int* __restrict__ batch,
                                                    float* __restrict__ out,
                                                    float* __restrict__ hs, int M) {
    const int K = HID;
    __shared__ unsigned short As[4][64][8];
    __shared__ unsigned short Bs[4][128][8];
    int tid = threadIdx.x;
    int wave = tid >> 6;
    int lane = tid & 63;
    int quad = lane >> 4;
    int l15 = lane & 15;
    int m0 = blockIdx.x * 64;

    f32x4 acc[8];
#pragma unroll
    for (int nt = 0; nt < 8; ++nt) acc[nt] = (f32x4){0.f, 0.f, 0.f, 0.f};

    int gm_a = m0 + lane; if (gm_a >= M) gm_a = M - 1;
    const unsigned short* ap_base = G + (size_t)gm_a * K + wave * 8;

    for (int k0 = 0; k0 < K; k0 += 32) {
        *(short8*)&As[wave][lane][0] = *(const short8*)(ap_base + k0);
#pragma unroll
        for (int i = 0; i < 2; ++i) {
            int slot = tid + i * 256;
            int bkq = slot >> 7;
            int n = slot & 127;
            *(short8*)&Bs[bkq][n][0] = *(const short8*)(Bt + (size_t)n * K + k0 + bkq * 8);
        }
        __syncthreads();
        short8 a = *(short8*)&As[quad][wave * 16 + l15][0];
#pragma unroll
        for (int nt = 0; nt < 8; ++nt) {
            short8 b = *(short8*)&Bs[quad][nt * 16 + l15][0];
            acc[nt] = __builtin_amdgcn_mfma_f32_16x16x32_bf16(a, b, acc[nt], 0, 0, 0);
        }
        __syncthreads();
    }
    int rb = m0 + wave * 16 + quad * 4;
    int g_[4];
#pragma unroll
    for (int r2 = 0; r2 < 4; ++r2)
        g_[r2] = (rb + r2 < M) ? batch[rb + r2] : -1;
#pragma unroll
    for (int nt = 0; nt < 8; ++nt) {
        int colb = nt * 16 + l15;
        float bcol = bias[colb];
        float v[4];
#pragma unroll
        for (int r2 = 0; r2 < 4; ++r2) {
            v[r2] = acc[nt][r2] + bcol;
            if (rb + r2 < M) out[(size_t)(rb + r2) * 128 + colb] = v[r2];
        }
        float run = v[0];
        int gcur = g_[0];
#pragma unroll
        for (int r2 = 1; r2 < 4; ++r2) {
            if (g_[r2] == gcur) run += v[r2];
            else {
                if (gcur >= 0) atomicAdd(&hs[(size_t)gcur * 128 + colb], run);
                gcur = g_[r2]; run = v[r2];
            }
        }
        if (gcur >= 0) atomicAdd(&hs[(size_t)gcur * 128 + colb], run);
    }
}

// ---------------- aggregation: one WAVE per node, packed bf16x2 per lane ----------------

template <int RELU, int OUTBF>
__global__ __launch_bounds__(128) void k_agg(const unsigned* __restrict__ t,
                                             const int* __restrict__ offs,
                                             const int* __restrict__ srcIdx,
                                             const float* __restrict__ dinv,
                                             const float* __restrict__ bias,
                                             void* __restrict__ out_) {
    int wave = threadIdx.x >> 6;
    int lane = threadIdx.x & 63;
    int i = blockIdx.x * 2 + wave;
    float di = dinv[i];
    unsigned self = t[(size_t)i * 64 + lane];
    float s0 = bf2f(self & 0xffffu) * di;
    float s1 = bf2f(self >> 16) * di;
    int lo = offs[i], hi = offs[i + 1];
    int e = lo;
    for (; e + 8 <= hi; e += 8) {
        int idx[8];
#pragma unroll
        for (int j = 0; j < 8; ++j) idx[j] = srcIdx[e + j];
        unsigned v[8];
#pragma unroll
        for (int j = 0; j < 8; ++j) v[j] = t[(size_t)idx[j] * 64 + lane];
        float d[8];
#pragma unroll
        for (int j = 0; j < 8; ++j) d[j] = dinv[idx[j]];
#pragma unroll
        for (int j = 0; j < 8; ++j) {
            s0 = fmaf(bf2f(v[j] & 0xffffu), d[j], s0);
            s1 = fmaf(bf2f(v[j] >> 16), d[j], s1);
        }
    }
    for (; e < hi; ++e) {
        int sn = srcIdx[e];
        unsigned vv = t[(size_t)sn * 64 + lane];
        float dd = dinv[sn];
        s0 = fmaf(bf2f(vv & 0xffffu), dd, s0);
        s1 = fmaf(bf2f(vv >> 16), dd, s1);
    }
    float r0 = s0 * di;
    float r1 = s1 * di;
    if (bias) {
        float2 bb = *(const float2*)(bias + lane * 2);
        r0 += bb.x; r1 += bb.y;
    }
    if (RELU) { r0 = fmaxf(r0, 0.f); r1 = fmaxf(r1, 0.f); }
    if (OUTBF) {
        unsigned o = (unsigned)f2bf(r0) | ((unsigned)f2bf(r1) << 16);
        ((unsigned*)out_)[(size_t)i * 64 + lane] = o;
    } else {
        *(float2*)((float*)out_ + (size_t)i * 128 + lane * 2) = make_float2(r0, r1);
    }
}

// ---------------- launch ----------------

extern "C" void kernel_launch(void* const* d_in, const int* in_sizes, int n_in,
                              void* d_out, int out_size, void* d_ws, size_t ws_size,
                              hipStream_t stream) {
    const float* x  = (const float*)d_in[0];
    const float* W1 = (const float*)d_in[1];
    const float* b1 = (const float*)d_in[2];
    const float* W2 = (const float*)d_in[3];
    const float* b2 = (const float*)d_in[4];
    const int*   ei = (const int*)d_in[5];
    const int*   batch = (const int*)d_in[6];
    const int* row = ei;
    const int* col = ei + N_EDGES;

    float* out_hs = (float*)d_out;
    float* out_h  = (float*)d_out + N_GRAPHS * OUT_FEATS;

    char* ws = (char*)d_ws;
    unsigned short* tb   = (unsigned short*)ws;                  // 12,800,000
    unsigned short* h1b  = (unsigned short*)(ws + 12800000);     // 12,800,000
    unsigned short* gb   = (unsigned short*)(ws + 25600000);     // 12,800,000
    float* dinv = (float*)(ws + 38400000);
    int*   cnt    = (int*)(ws + 38600000);
    int*   offs   = (int*)(ws + 38800000);
    int*   cursor = (int*)(ws + 39000016);
    int*   srcIdx = (int*)(ws + 39200016);
    int*   gstart = (int*)(ws + 41760016);
    int*   bsum   = (int*)(ws + 41761056);
    unsigned short* wt1 = (unsigned short*)(ws + 41761472);
    unsigned short* wt2 = (unsigned short*)(ws + 41892544);

    const int TB = 256;
    k_prep<<<PREP_BLOCKS, 256, 0, stream>>>(W1, W2, batch, wt1, wt2, cnt, gstart, out_hs);
    k_count<<<(N_EDGES / 4 + TB - 1) / TB, TB, 0, stream>>>(col, cnt);
    k_scan_a<<<SCAN_BLOCKS, 256, 0, stream>>>(cnt, offs, bsum);
    k_scan_c<<<SCAN_BLOCKS, 256, 0, stream>>>(cnt, bsum, offs, cursor, dinv);
    k_fill<<<(N_EDGES / 4 + TB - 1) / TB, TB, 0, stream>>>(row, col, cursor, srcIdx);

    // layer 1: 128-tile MFMA GEMM, then agg (+b1, ReLU) -> bf16 h1
    k_gemm1<IN_FEATS><<<(N_NODES + 127) / 128, 256, 0, stream>>>(x, wt1, tb, N_NODES);
    k_agg<1, 1><<<N_NODES / 2, 128, 0, stream>>>((const unsigned*)tb, offs, srcIdx, dinv, b1, h1b);
    // layer 2 (commuted): agg h1 (no bias) -> g, then GEMM2 (+b2) with fused pool
    k_agg<0, 1><<<N_NODES / 2, 128, 0, stream>>>((const unsigned*)h1b, offs, srcIdx, dinv, nullptr, gb);
    k_gemm2_pool<<<(N_NODES + 63) / 64, 256, 0, stream>>>(gb, wt2, b2, batch, out_h, out_hs, N_NODES);
}

// Round 8
// 327.962 us; speedup vs baseline: 2.0461x; 1.0537x over previous
//
#include <hip/hip_runtime.h>
#include <hip/hip_bf16.h>

#define N_NODES  50000
#define N_EDGES  640000
#define IN_FEATS 512
#define HID      128
#define OUT_FEATS 128
#define N_GRAPHS 256

#define SCAN_CHUNK 1024
#define SCAN_BLOCKS ((N_NODES + SCAN_CHUNK - 1) / SCAN_CHUNK)   // 49

typedef __attribute__((ext_vector_type(8))) short short8;
typedef __attribute__((ext_vector_type(4))) float f32x4;

__device__ __forceinline__ float bf2f(unsigned u16) {
    return __uint_as_float(u16 << 16);
}
__device__ __forceinline__ unsigned short f2bf(float f) {
    __hip_bfloat16 h = __float2bfloat16(f);
    return *(unsigned short*)&h;
}

// ---------------- fused preprocessing: zero cnt | cvt W1 | cvt W2 | zero hs ----
// ranges: [0,196) zero cnt, [196,452) cvt1, [452,516) cvt2, [516,644) zero hs
#define PREP_BLOCKS 644

__global__ __launch_bounds__(256) void k_prep(const float* __restrict__ W1,
                                              const float* __restrict__ W2,
                                              unsigned short* __restrict__ wt1,
                                              unsigned short* __restrict__ wt2,
                                              int* __restrict__ cnt,
                                              float* __restrict__ hs) {
    int b = blockIdx.x;
    int t = threadIdx.x;
    if (b < 196) {
        int i = b * 256 + t;
        if (i < N_NODES) cnt[i] = 0;
    } else if (b < 452) {
        int idx = (b - 196) * 256 + t;
        int n = idx & 127, k = idx >> 7;
        wt1[(size_t)n * IN_FEATS + k] = f2bf(W1[(size_t)k * 128 + n]);
    } else if (b < 516) {
        int idx = (b - 452) * 256 + t;
        int n = idx & 127, k = idx >> 7;
        wt2[(size_t)n * HID + k] = f2bf(W2[(size_t)k * 128 + n]);
    } else {
        int idx = (b - 516) * 256 + t;
        hs[idx] = 0.f;
    }
}

// ------- FAT kernel: GEMM1 (128x128 tile, blocks [0,nblk)) + edge count (rest) -------
// gemm: Cb[M,128]bf16 = A[M,K]fp32 @ Bt[128][K]bf16^T

template <int K>
__global__ __launch_bounds__(256) void k_g1c(const float* __restrict__ A,
                                             const unsigned short* __restrict__ Bt,
                                             unsigned short* __restrict__ Cb, int M,
                                             const int* __restrict__ col,
                                             int* __restrict__ cnt, int nblk_gemm) {
    __shared__ unsigned short As[4][128][8];   // 8 KB
    __shared__ unsigned short Bs[4][128][8];   // 8 KB
    int tid = threadIdx.x;

    if (blockIdx.x >= nblk_gemm) {
        // -------- edge count part --------
        int e4 = ((blockIdx.x - nblk_gemm) * 256 + tid) * 4;
        if (e4 < N_EDGES) {
            int4 c = *(const int4*)(col + e4);
            atomicAdd(&cnt[c.x], 1);
            atomicAdd(&cnt[c.y], 1);
            atomicAdd(&cnt[c.z], 1);
            atomicAdd(&cnt[c.w], 1);
        }
        return;
    }

    // -------- gemm1 part --------
    int wave = tid >> 6;
    int lane = tid & 63;
    int quad = lane >> 4;
    int l15 = lane & 15;
    int m0 = blockIdx.x * 128;
    int mw = (wave >> 1) * 64;
    int nw = (wave & 1) * 64;

    f32x4 acc[4][4];
#pragma unroll
    for (int i = 0; i < 4; ++i)
#pragma unroll
        for (int j = 0; j < 4; ++j) acc[i][j] = (f32x4){0.f, 0.f, 0.f, 0.f};

    int r0s = tid >> 2, kq0 = tid & 3;
    int r1s = r0s + 64;
    int gm0 = m0 + r0s; if (gm0 >= M) gm0 = M - 1;
    int gm1 = m0 + r1s; if (gm1 >= M) gm1 = M - 1;
    const float* ap0 = A + (size_t)gm0 * K + kq0 * 8;
    const float* ap1 = A + (size_t)gm1 * K + kq0 * 8;

    for (int k0 = 0; k0 < K; k0 += 32) {
        {
            float4 v0 = *(const float4*)(ap0 + k0);
            float4 v1 = *(const float4*)(ap0 + k0 + 4);
            float f[8] = {v0.x, v0.y, v0.z, v0.w, v1.x, v1.y, v1.z, v1.w};
            short8 pk;
#pragma unroll
            for (int j = 0; j < 8; ++j) pk[j] = (short)f2bf(f[j]);
            *(short8*)&As[kq0][r0s][0] = pk;
            v0 = *(const float4*)(ap1 + k0);
            v1 = *(const float4*)(ap1 + k0 + 4);
            float g[8] = {v0.x, v0.y, v0.z, v0.w, v1.x, v1.y, v1.z, v1.w};
#pragma unroll
            for (int j = 0; j < 8; ++j) pk[j] = (short)f2bf(g[j]);
            *(short8*)&As[kq0][r1s][0] = pk;
        }
#pragma unroll
        for (int i = 0; i < 2; ++i) {
            int slot = tid + i * 256;
            int n = slot >> 2, kq = slot & 3;
            *(short8*)&Bs[kq][n][0] = *(const short8*)(Bt + (size_t)n * K + k0 + kq * 8);
        }
        __syncthreads();
        short8 af[4], bfr[4];
#pragma unroll
        for (int i = 0; i < 4; ++i) af[i] = *(short8*)&As[quad][mw + i * 16 + l15][0];
#pragma unroll
        for (int j = 0; j < 4; ++j) bfr[j] = *(short8*)&Bs[quad][nw + j * 16 + l15][0];
#pragma unroll
        for (int i = 0; i < 4; ++i)
#pragma unroll
            for (int j = 0; j < 4; ++j)
                acc[i][j] = __builtin_amdgcn_mfma_f32_16x16x32_bf16(af[i], bfr[j], acc[i][j], 0, 0, 0);
        __syncthreads();
    }
#pragma unroll
    for (int i = 0; i < 4; ++i) {
        int rb = m0 + mw + i * 16 + quad * 4;
#pragma unroll
        for (int j = 0; j < 4; ++j) {
            int colb = nw + j * 16 + l15;
#pragma unroll
            for (int r2 = 0; r2 < 4; ++r2) {
                int gm = rb + r2;
                if (gm < M) Cb[(size_t)gm * 128 + colb] = f2bf(acc[i][j][r2]);
            }
        }
    }
}

// ---------------- scan ----------------

__global__ __launch_bounds__(256) void k_scan_a(const int* __restrict__ cnt,
                                                int* __restrict__ offs,
                                                int* __restrict__ bsum) {
    __shared__ int sums[256];
    int t = threadIdx.x;
    int base = blockIdx.x * SCAN_CHUNK + t * 4;
    int c0 = 0, c1 = 0, c2 = 0, c3 = 0;
    if (base + 3 < N_NODES) {
        int4 v = *(const int4*)(cnt + base);
        c0 = v.x; c1 = v.y; c2 = v.z; c3 = v.w;
    } else {
        if (base + 0 < N_NODES) c0 = cnt[base + 0];
        if (base + 1 < N_NODES) c1 = cnt[base + 1];
        if (base + 2 < N_NODES) c2 = cnt[base + 2];
    }
    int ts = c0 + c1 + c2 + c3;
    sums[t] = ts;
    __syncthreads();
#pragma unroll
    for (int off = 1; off < 256; off <<= 1) {
        int add = (t >= off) ? sums[t - off] : 0;
        __syncthreads();
        sums[t] += add;
        __syncthreads();
    }
    int ex = sums[t] - ts;
    if (base + 3 < N_NODES) {
        int4 o;
        o.x = ex; o.y = ex + c0; o.z = ex + c0 + c1; o.w = ex + c0 + c1 + c2;
        *(int4*)(offs + base) = o;
    } else {
        if (base + 0 < N_NODES) offs[base + 0] = ex;
        if (base + 1 < N_NODES) offs[base + 1] = ex + c0;
        if (base + 2 < N_NODES) offs[base + 2] = ex + c0 + c1;
    }
    if (t == 255) bsum[blockIdx.x] = sums[255];
}

__global__ __launch_bounds__(256) void k_scan_c(const int* __restrict__ cnt,
                                                const int* __restrict__ bsum,
                                                int* __restrict__ offs,
                                                int* __restrict__ cursor,
                                                float* __restrict__ dinv) {
    __shared__ int sb[64];
    int t = threadIdx.x;
    int b = blockIdx.x;
    if (t < 64) sb[t] = (t < SCAN_BLOCKS) ? bsum[t] : 0;
    __syncthreads();
#pragma unroll
    for (int off = 1; off < 64; off <<= 1) {
        int add = 0;
        if (t < 64 && t >= off) add = sb[t - off];
        __syncthreads();
        if (t < 64) sb[t] += add;
        __syncthreads();
    }
    int add = (b == 0) ? 0 : sb[b - 1];
    int base = b * SCAN_CHUNK + t * 4;
    if (base + 3 < N_NODES) {
        int4 o = *(const int4*)(offs + base);
        o.x += add; o.y += add; o.z += add; o.w += add;
        *(int4*)(offs + base) = o;
        *(int4*)(cursor + base) = o;
        int4 c = *(const int4*)(cnt + base);
        float4 d;
        d.x = rsqrtf((float)c.x + 1.0f);
        d.y = rsqrtf((float)c.y + 1.0f);
        d.z = rsqrtf((float)c.z + 1.0f);
        d.w = rsqrtf((float)c.w + 1.0f);
        *(float4*)(dinv + base) = d;
    } else {
#pragma unroll
        for (int j = 0; j < 4; ++j) {
            int i = base + j;
            if (i < N_NODES) {
                int o = offs[i] + add;
                offs[i] = o; cursor[i] = o;
                dinv[i] = rsqrtf((float)cnt[i] + 1.0f);
            }
        }
    }
    if (b == 0 && t == 0) offs[N_NODES] = N_EDGES;
}

__global__ void k_fill(const int* __restrict__ row, const int* __restrict__ col,
                       int* __restrict__ cursor, int* __restrict__ srcIdx) {
    int e4 = (blockIdx.x * blockDim.x + threadIdx.x) * 4;
    if (e4 >= N_EDGES) return;
    int4 r = *(const int4*)(row + e4);
    int4 c = *(const int4*)(col + e4);
    srcIdx[atomicAdd(&cursor[c.x], 1)] = r.x;
    srcIdx[atomicAdd(&cursor[c.y], 1)] = r.y;
    srcIdx[atomicAdd(&cursor[c.z], 1)] = r.z;
    srcIdx[atomicAdd(&cursor[c.w], 1)] = r.w;
}

// ---------------- aggregation: one WAVE per node, 2 edges/iter (half-wave parity) ----
// t rows are 64 uints (128 bf16). Lane l=lane&31 covers uints [2l,2l+1] = feats 4l..4l+3;
// half h=lane>>5 takes edge e+h. Predicated 16-edge chunks: invalid slots gather own row
// with weight 0 (cache-hot, exact). Cross-half combine via shfl_xor 32.

template <int RELU>
__global__ __launch_bounds__(256) void k_agg(const unsigned* __restrict__ t,
                                             const int* __restrict__ offs,
                                             const int* __restrict__ srcIdx,
                                             const float* __restrict__ dinv,
                                             const float* __restrict__ bias,
                                             unsigned* __restrict__ out_) {
    int wave = threadIdx.x >> 6;
    int lane = threadIdx.x & 63;
    int h = lane >> 5;
    int l = lane & 31;
    int i = blockIdx.x * 4 + wave;          // N_NODES % 4 == 0
    float di = dinv[i];
    const unsigned* my = t + (size_t)i * 64 + 2 * l;

    float s0 = 0.f, s1 = 0.f, s2 = 0.f, s3 = 0.f;
    {   // self term, half 0 only
        uint2 sv = *(const uint2*)my;
        if (h == 0) {
            s0 = bf2f(sv.x & 0xffffu) * di;
            s1 = bf2f(sv.x >> 16) * di;
            s2 = bf2f(sv.y & 0xffffu) * di;
            s3 = bf2f(sv.y >> 16) * di;
        }
    }
    int lo = offs[i], hi = offs[i + 1];
    for (int e = lo; e < hi; e += 16) {
        int idx[8];
        float d[8];
        uint2 v[8];
#pragma unroll
        for (int j = 0; j < 8; ++j) {
            int ee = e + 2 * j + h;
            idx[j] = (ee < hi) ? srcIdx[ee] : i;     // self row when invalid
        }
#pragma unroll
        for (int j = 0; j < 8; ++j)
            v[j] = *(const uint2*)(t + (size_t)idx[j] * 64 + 2 * l);
#pragma unroll
        for (int j = 0; j < 8; ++j) {
            int ee = e + 2 * j + h;
            d[j] = (ee < hi) ? dinv[idx[j]] : 0.f;   // weight 0 when invalid
        }
#pragma unroll
        for (int j = 0; j < 8; ++j) {
            s0 = fmaf(bf2f(v[j].x & 0xffffu), d[j], s0);
            s1 = fmaf(bf2f(v[j].x >> 16),     d[j], s1);
            s2 = fmaf(bf2f(v[j].y & 0xffffu), d[j], s2);
            s3 = fmaf(bf2f(v[j].y >> 16),     d[j], s3);
        }
    }
    // combine the two halves
    s0 += __shfl_xor(s0, 32);
    s1 += __shfl_xor(s1, 32);
    s2 += __shfl_xor(s2, 32);
    s3 += __shfl_xor(s3, 32);

    float r0 = s0 * di, r1 = s1 * di, r2 = s2 * di, r3 = s3 * di;
    if (bias) {
        float4 bb = *(const float4*)(bias + 4 * l);
        r0 += bb.x; r1 += bb.y; r2 += bb.z; r3 += bb.w;
    }
    if (RELU) {
        r0 = fmaxf(r0, 0.f); r1 = fmaxf(r1, 0.f);
        r2 = fmaxf(r2, 0.f); r3 = fmaxf(r3, 0.f);
    }
    if (h == 0) {
        uint2 o;
        o.x = (unsigned)f2bf(r0) | ((unsigned)f2bf(r1) << 16);
        o.y = (unsigned)f2bf(r2) | ((unsigned)f2bf(r3) << 16);
        *(uint2*)(out_ + (size_t)i * 64 + 2 * l) = o;
    }
}

// ------- GEMM2 + bias + fused pool: out[M,128]f32 = G[M,128]bf16 @ Bt^T + b;
//         hs[batch[m]] += out[m]  (rows batch-sorted -> grouped atomics) -------

__global__ __launch_bounds__(256) void k_gemm2_pool(const unsigned short* __restrict__ G,
                                                    const unsigned short* __restrict__ Bt,
                                                    const float* __restrict__ bias,
                                                    const int* __restrict__ batch,
                                                    float* __restrict__ out,
                                                    float* __restrict__ hs, int M) {
    const int K = HID;
    __shared__ unsigned short As[4][64][8];
    __shared__ unsigned short Bs[4][128][8];
    int tid = threadIdx.x;
    int wave = tid >> 6;
    int lane = tid & 63;
    int quad = lane >> 4;
    int l15 = lane & 15;
    int m0 = blockIdx.x * 64;

    f32x4 acc[8];
#pragma unroll
    for (int nt = 0; nt < 8; ++nt) acc[nt] = (f32x4){0.f, 0.f, 0.f, 0.f};

    int gm_a = m0 + lane; if (gm_a >= M) gm_a = M - 1;
    const unsigned short* ap_base = G + (size_t)gm_a * K + wave * 8;

    for (int k0 = 0; k0 < K; k0 += 32) {
        *(short8*)&As[wave][lane][0] = *(const short8*)(ap_base + k0);
#pragma unroll
        for (int i = 0; i < 2; ++i) {
            int slot = tid + i * 256;
            int bkq = slot >> 7;
            int n = slot & 127;
            *(short8*)&Bs[bkq][n][0] = *(const short8*)(Bt + (size_t)n * K + k0 + bkq * 8);
        }
        __syncthreads();
        short8 a = *(short8*)&As[quad][wave * 16 + l15][0];
#pragma unroll
        for (int nt = 0; nt < 8; ++nt) {
            short8 b = *(short8*)&Bs[quad][nt * 16 + l15][0];
            acc[nt] = __builtin_amdgcn_mfma_f32_16x16x32_bf16(a, b, acc[nt], 0, 0, 0);
        }
        __syncthreads();
    }
    int rb = m0 + wave * 16 + quad * 4;
    int g_[4];
#pragma unroll
    for (int r2 = 0; r2 < 4; ++r2)
        g_[r2] = (rb + r2 < M) ? batch[rb + r2] : -1;
#pragma unroll
    for (int nt = 0; nt < 8; ++nt) {
        int colb = nt * 16 + l15;
        float bcol = bias[colb];
        float v[4];
#pragma unroll
        for (int r2 = 0; r2 < 4; ++r2) {
            v[r2] = acc[nt][r2] + bcol;
            if (rb + r2 < M) out[(size_t)(rb + r2) * 128 + colb] = v[r2];
        }
        float run = v[0];
        int gcur = g_[0];
#pragma unroll
        for (int r2 = 1; r2 < 4; ++r2) {
            if (g_[r2] == gcur) run += v[r2];
            else {
                if (gcur >= 0) atomicAdd(&hs[(size_t)gcur * 128 + colb], run);
                gcur = g_[r2]; run = v[r2];
            }
        }
        if (gcur >= 0) atomicAdd(&hs[(size_t)gcur * 128 + colb], run);
    }
}

// ---------------- launch ----------------

extern "C" void kernel_launch(void* const* d_in, const int* in_sizes, int n_in,
                              void* d_out, int out_size, void* d_ws, size_t ws_size,
                              hipStream_t stream) {
    const float* x  = (const float*)d_in[0];
    const float* W1 = (const float*)d_in[1];
    const float* b1 = (const float*)d_in[2];
    const float* W2 = (const float*)d_in[3];
    const float* b2 = (const float*)d_in[4];
    const int*   ei = (const int*)d_in[5];
    const int*   batch = (const int*)d_in[6];
    const int* row = ei;
    const int* col = ei + N_EDGES;

    float* out_hs = (float*)d_out;
    float* out_h  = (float*)d_out + N_GRAPHS * OUT_FEATS;

    char* ws = (char*)d_ws;
    unsigned short* tb   = (unsigned short*)ws;                  // 12,800,000
    unsigned short* h1b  = (unsigned short*)(ws + 12800000);     // 12,800,000
    unsigned short* gb   = (unsigned short*)(ws + 25600000);     // 12,800,000
    float* dinv = (float*)(ws + 38400000);
    int*   cnt    = (int*)(ws + 38600000);
    int*   offs   = (int*)(ws + 38800000);
    int*   cursor = (int*)(ws + 39000016);
    int*   srcIdx = (int*)(ws + 39200016);
    int*   bsum   = (int*)(ws + 41761056);
    unsigned short* wt1 = (unsigned short*)(ws + 41761472);
    unsigned short* wt2 = (unsigned short*)(ws + 41892544);

    const int TB = 256;
    const int GB1 = (N_NODES + 127) / 128;               // 391 gemm blocks
    const int CB  = (N_EDGES / 4 + TB - 1) / TB;         // 625 count blocks

    k_prep<<<PREP_BLOCKS, 256, 0, stream>>>(W1, W2, wt1, wt2, cnt, out_hs);
    // gemm1 + edge-count fat kernel (independent work, concurrent)
    k_g1c<IN_FEATS><<<GB1 + CB, 256, 0, stream>>>(x, wt1, tb, N_NODES, col, cnt, GB1);
    k_scan_a<<<SCAN_BLOCKS, 256, 0, stream>>>(cnt, offs, bsum);
    k_scan_c<<<SCAN_BLOCKS, 256, 0, stream>>>(cnt, bsum, offs, cursor, dinv);
    k_fill<<<(N_EDGES / 4 + TB - 1) / TB, TB, 0, stream>>>(row, col, cursor, srcIdx);

    // layer 1 agg (+b1, ReLU) -> bf16 h1
    k_agg<1><<<N_NODES / 4, 256, 0, stream>>>((const unsigned*)tb, offs, srcIdx, dinv, b1, (unsigned*)h1b);
    // layer 2 (commuted): agg h1 (no bias) -> g, then GEMM2 (+b2) with fused pool
    k_agg<0><<<N_NODES / 4, 256, 0, stream>>>((const unsigned*)h1b, offs, srcIdx, dinv, nullptr, (unsigned*)gb);
    k_gemm2_pool<<<(N_NODES + 63) / 64, 256, 0, stream>>>(gb, wt2, b2, batch, out_h, out_hs, N_NODES);
}